// Round 7
// baseline (309.345 us; speedup 1.0000x reference)
//
#include <hip/hip_runtime.h>
#include <stdint.h>

// Problem constants
#define B_    64
#define N_    512
#define DIM_  256
#define H_    8
#define DH_   64
#define INNER_ 512

typedef __attribute__((ext_vector_type(8))) short bf16x8;
typedef __attribute__((ext_vector_type(4))) float f32x4;
typedef __attribute__((ext_vector_type(4))) short s16x4;

typedef const __attribute__((address_space(1))) void* gas_ptr;
typedef __attribute__((address_space(3))) void* las_ptr;

__device__ __forceinline__ short f2bf(float f) {
  unsigned int u = __float_as_uint(f);
  u += 0x7fffu + ((u >> 16) & 1u);          // RNE
  return (short)(u >> 16);
}
__device__ __forceinline__ float bf2f(short s) {
  return __uint_as_float(((unsigned int)(unsigned short)s) << 16);
}
__device__ __forceinline__ void cp16(const void* g, void* l) {
  __builtin_amdgcn_global_load_lds((gas_ptr)g, (las_ptr)l, 16, 0, 0);
}
__device__ __forceinline__ f32x4 mfma16(bf16x8 a, bf16x8 b, f32x4 c) {
  return __builtin_amdgcn_mfma_f32_16x16x32_bf16(a, b, c, 0, 0, 0);
}

// ---------------------------------------------------------------------------
// Prep: fp32 -> bf16 edge conversions (+ scaled bias copy, float mask).
// ---------------------------------------------------------------------------
#define PREP_WT1  (2048 * 256)
#define PREP_WOT  (256 * 512)
#define PREP_X    (32768 * 256)
#define PREP_BIAS (8 * 512 * 512)
#define PREP_MASK (64 * 512)
#define PREP_TOT  (PREP_WT1 + PREP_WOT + PREP_X + PREP_BIAS + PREP_MASK)

__global__ void prep_k(const float* __restrict__ x,
                       const float* __restrict__ Wq, const float* __restrict__ Wkv,
                       const float* __restrict__ Wg, const float* __restrict__ Wo,
                       const float* __restrict__ bias, const int* __restrict__ mask,
                       short* __restrict__ Wt1, short* __restrict__ WoT,
                       short* __restrict__ xb, float* __restrict__ biasS,
                       float* __restrict__ maskF)
{
  const int idx = blockIdx.x * 256 + threadIdx.x;
  if (idx < PREP_WT1) {
    const int n = idx >> 8, k = idx & 255;
    float v;
    if (n < 512)        v = Wq[k * 512 + n];
    else if (n < 1536)  v = Wkv[k * 1024 + (n - 512)];   // K cols then V cols
    else                v = Wg[k * 512 + (n - 1536)];
    Wt1[idx] = f2bf(v);
  } else if (idx < PREP_WT1 + PREP_WOT) {
    const int j = idx - PREP_WT1;
    const int n = j >> 9, k = j & 511;
    WoT[j] = f2bf(Wo[k * 256 + n]);
  } else if (idx < PREP_WT1 + PREP_WOT + PREP_X) {
    const int j = idx - (PREP_WT1 + PREP_WOT);
    xb[j] = f2bf(x[j]);
  } else if (idx < PREP_WT1 + PREP_WOT + PREP_X + PREP_BIAS) {
    const int j = idx - (PREP_WT1 + PREP_WOT + PREP_X);
    biasS[j] = bias[j] * 1.4426950408889634f;            // coalesced scaled copy
  } else if (idx < PREP_TOT) {
    const int j = idx - (PREP_WT1 + PREP_WOT + PREP_X + PREP_BIAS);
    maskF[j] = mask[j] ? 1.0f : 0.0f;
  }
}

// ---------------------------------------------------------------------------
// GEMM1: C = xb[32768,256] @ Wt1^T  (N=2048 fused Q|K|V|G), all bf16.
// Q/K/G regions use SWAPPED MFMA operands (transposed C) -> s16x4 stores.
// (Frozen.)
// ---------------------------------------------------------------------------
__global__ __launch_bounds__(256, 2) void gemm_qkvg(
    const short* __restrict__ X, const short* __restrict__ Wt,
    const float* __restrict__ bg,
    short* __restrict__ Q, short* __restrict__ Kb,
    short* __restrict__ Vt, short* __restrict__ G)
{
  __shared__ __align__(16) short As[128 * 32];
  __shared__ __align__(16) short Bs[128 * 32];
  const int tid = threadIdx.x;
  const int w = tid >> 6, lane = tid & 63;
  const int m = lane & 15, q = lane >> 4;
  const int n0 = blockIdx.x * 128, m0 = blockIdx.y * 128;
  const int region = blockIdx.x >> 2;           // 0=Q 1=K 2=V 3=G
  const bool vreg = (region == 2);
  const int ric = lane >> 2, cslot = lane & 3;
  const int csw = cslot ^ ((ric >> 1) & 3);
  const int wr = (w >> 1) * 64, wc = (w & 1) * 64;
  const int rsw = (m >> 1) & 3;
  f32x4 acc[4][4] = {};
  for (int k0 = 0; k0 < DIM_; k0 += 32) {
    __syncthreads();
#pragma unroll
    for (int s = 0; s < 2; ++s) {
      const int rr = w * 32 + s * 16;
      cp16(X  + (size_t)(m0 + rr + ric) * DIM_ + (k0 + csw * 8), &As[rr * 32]);
      cp16(Wt + (size_t)(n0 + rr + ric) * DIM_ + (k0 + csw * 8), &Bs[rr * 32]);
    }
    __syncthreads();
    bf16x8 af[4], bfv[4];
#pragma unroll
    for (int t = 0; t < 4; ++t) {
      af[t]  = *(const bf16x8*)&As[(wr + t * 16 + m) * 32 + ((q ^ rsw) * 8)];
      bfv[t] = *(const bf16x8*)&Bs[(wc + t * 16 + m) * 32 + ((q ^ rsw) * 8)];
    }
    if (vreg) {
#pragma unroll
      for (int ti = 0; ti < 4; ++ti)
#pragma unroll
        for (int tj = 0; tj < 4; ++tj)
          acc[ti][tj] = mfma16(af[ti], bfv[tj], acc[ti][tj]);
    } else {
#pragma unroll
      for (int ti = 0; ti < 4; ++ti)
#pragma unroll
        for (int tj = 0; tj < 4; ++tj)
          acc[ti][tj] = mfma16(bfv[tj], af[ti], acc[ti][tj]);  // transposed C
    }
  }
  if (vreg) {                                    // V -> transposed [B,H,DH,N]
    const int cb = (n0 & 511) + wc;
#pragma unroll
    for (int ti = 0; ti < 4; ++ti) {
      const int mgb = m0 + wr + ti * 16 + q * 4;
      const int b = mgb >> 9, n = mgb & 511;
#pragma unroll
      for (int tj = 0; tj < 4; ++tj) {
        const int c = cb + tj * 16 + m;
        const int h = c >> 6, d = c & 63;
        s16x4 st;
#pragma unroll
        for (int r = 0; r < 4; ++r) st[r] = f2bf(acc[ti][tj][r]);
        *(s16x4*)&Vt[((size_t)(b * 8 + h) * 64 + d) * 512 + n] = st;
      }
    }
  } else {                                       // Q / K / G: transposed C
#pragma unroll
    for (int ti = 0; ti < 4; ++ti) {
      const int xrow = m0 + wr + ti * 16 + m;    // one x-row per lane
      const int b = xrow >> 9, n = xrow & 511;
#pragma unroll
      for (int tj = 0; tj < 4; ++tj) {
        const int cvec = (n0 & 511) + wc + tj * 16 + q * 4;  // 4 consecutive cols
        if (region == 3) {                       // gates = x@Wg + bg
          const f32x4 bg4 = *(const f32x4*)&bg[cvec];
          s16x4 st;
#pragma unroll
          for (int r = 0; r < 4; ++r) st[r] = f2bf(acc[ti][tj][r] + bg4[r]);
          *(s16x4*)&G[(size_t)xrow * 512 + cvec] = st;
        } else {
          const int h = cvec >> 6, d0 = cvec & 63;
          s16x4 st;
#pragma unroll
          for (int r = 0; r < 4; ++r) st[r] = f2bf(acc[ti][tj][r]);
          short* dst = (region == 0) ? Q : Kb;
          *(s16x4*)&dst[((size_t)(b * 8 + h) * 512 + n) * 64 + d0] = st;
        }
      }
    }
  }
}

// ---------------------------------------------------------------------------
// Attention, flash-style, TRANSPOSED score MFMA (S^T = K·Q^T). KVBLK=32.
// R5 structure (2-slot dbuf, 20KB LDS, __syncthreads; R6 ring reverted).
// NEW (issue-demand reduction): the row-sum l is computed by MFMA with a
// ones B-operand on the already-loaded P fragment:
//     lacc[it] = mfma16(pa, ONES, lacc[it])
// replacing per-chunk 2x16 (and+add) VALU ops + a serial dep chain. Result
// lands in o's lane layout (row = q*4+r), so the epilogue shfl-reduce and
// broadcasts collapse to lr[r] = 1/lacc[it][r]. Exactness unchanged: pa IS
// the truncated stored P, so l == sum of stored P as before.
// ---------------------------------------------------------------------------
__global__ __launch_bounds__(256, 4) void attn_k(
    const short* __restrict__ Q, const short* __restrict__ K,
    const short* __restrict__ Vt, const float* __restrict__ biasS,
    const float* __restrict__ maskF, short* __restrict__ G)
{
  __shared__ __align__(16) short Ks[2][32 * 64];   // [j][d], xor-swizzled by j&7
  __shared__ __align__(16) short Vs[2][64 * 32];   // [d][j], slot-xor (d^d>>2)&3
  __shared__ __align__(16) short Pall[4][16 * 32]; // per-wave, slot-xor (i^i>>2)&3
  const int tid = threadIdx.x;
  const int w = tid >> 6, lane = tid & 63;
  const int m = lane & 15, q = lane >> 4;
  const int m7 = m & 7;
  const int vsw = (m ^ (m >> 2)) & 3;              // bank-spread swizzle, 64B rows
  const int h = blockIdx.x, iq = blockIdx.y, b = blockIdx.z;
  const int i0w = iq * 128 + w * 32;               // this wave's first Q row
  const size_t bh = (size_t)b * 8 + h;
  const short* Qp = Q + (bh * 512 + i0w) * 64;
  const short* Kp = K + bh * 512 * 64;
  const short* Vp = Vt + bh * 64 * 512;
  const float* mkp = maskF + b * 512;
  short* Ps = Pall[w];

  // K staging: wave w stages rows w*8..w*8+7 (128B rows, 8 chunks of 8 shorts)
  const int srow = lane >> 3;                      // 0..7
  const int gchunk = (lane & 7) ^ srow;            // global d-chunk (xor by row&7)
  // V staging: wave w stages rows w*16..w*16+15 (64B rows, 4 chunks of 8)
  const int vrow = lane >> 2;                      // 0..15
  const int gchunkV = (lane & 3) ^ ((vrow ^ (vrow >> 2)) & 3);

  // ONES B-operand for the l row-sum MFMA (bf16 1.0 = 0x3F80)
  bf16x8 vones;
#pragma unroll
  for (int r = 0; r < 8; ++r) vones[r] = (short)0x3F80;

  // Q frags (B-operand): lane holds Q[i=m][d=q*8+jj]
  bf16x8 qf[2][2];
#pragma unroll
  for (int it = 0; it < 2; ++it) {
    qf[it][0] = *(const bf16x8*)&Qp[(it * 16 + m) * 64 + q * 8];
    qf[it][1] = *(const bf16x8*)&Qp[(it * 16 + m) * 64 + 32 + q * 8];
  }
  float miF[2];
#pragma unroll
  for (int it = 0; it < 2; ++it) miF[it] = mkp[i0w + it * 16 + m];

  // stage chunk 0 (1 cp16 for K + 1 for V per wave)
  cp16(Kp + (size_t)(w * 8 + srow) * 64 + gchunk * 8, &Ks[0][w * 8 * 64]);
  cp16(Vp + (size_t)(w * 16 + vrow) * 512 + gchunkV * 8, &Vs[0][w * 16 * 32]);

  f32x4 o[2][4] = {};
  f32x4 lacc[2] = {};                              // l in o-layout (row = q*4+r)
  __syncthreads();                                 // chunk 0 staged

  const float SCL = 0.125f * 1.4426950408889634f;  // scale * log2(e)
  for (int c = 0; c < 16; ++c) {
    const int p = c & 1;
    if (c < 15) {                                  // prefetch next chunk
      const int jn = (c + 1) * 32;
      cp16(Kp + (size_t)(jn + w * 8 + srow) * 64 + gchunk * 8, &Ks[p ^ 1][w * 8 * 64]);
      cp16(Vp + (size_t)(w * 16 + vrow) * 512 + jn + gchunkV * 8, &Vs[p ^ 1][w * 16 * 32]);
    }
    // mask (f32x4 per jt): j = c*32 + jt*16 + q*4 + r
    f32x4 mjf[2];
#pragma unroll
    for (int jt = 0; jt < 2; ++jt)
      mjf[jt] = *(const f32x4*)&mkp[c * 32 + jt * 16 + q * 4];

    // QK^T (transposed): lane holds S[i = it*16+m][j = c*32 + jt*16 + q*4 + r]
    f32x4 s[2][2];
    __builtin_amdgcn_s_setprio(1);
#pragma unroll
    for (int jt = 0; jt < 2; ++jt) {
      const bf16x8 ka = *(const bf16x8*)&Ks[p][(jt * 16 + m) * 64 + ((q ^ m7) * 8)];
      const bf16x8 kb = *(const bf16x8*)&Ks[p][(jt * 16 + m) * 64 + (((4 + q) ^ m7) * 8)];
#pragma unroll
      for (int it = 0; it < 2; ++it) {
        f32x4 a = {};
        a = mfma16(ka, qf[it][0], a);
        s[it][jt] = mfma16(kb, qf[it][1], a);
      }
    }
    __builtin_amdgcn_s_setprio(0);
#pragma unroll
    for (int it = 0; it < 2; ++it) {
      // bias (fp32, prescaled by log2e, original [h][i][j] layout)
      const float* bp = biasS + ((size_t)h * 512 + i0w + it * 16 + m) * 512 + c * 32;
      f32x4 bv[2];
#pragma unroll
      for (int jt = 0; jt < 2; ++jt)
        bv[jt] = *(const f32x4*)&bp[jt * 16 + q * 4];
      // softmax terms -> packed b64 P writes (4 consecutive j per lane)
#pragma unroll
      for (int jt = 0; jt < 2; ++jt) {
        s16x4 st;
#pragma unroll
        for (int r = 0; r < 4; ++r) {
          const float v = fmaf(s[it][jt][r], SCL, bv[jt][r]);
          float e = exp2f(v) * mjf[jt][r];
          e = (miF[it] != 0.0f) ? e : 1.0f;        // fully-masked row -> uniform
          st[r] = (short)(__float_as_uint(e) >> 16);  // trunc pack (no l chain)
        }
        *(s16x4*)&Ps[m * 32 + (((jt * 2 + (q >> 1)) ^ vsw) * 8) + (q & 1) * 4] = st;
      }
      // PV for this i-tile: A = P rows i (j=0..31), B = V^T cols d.
      // l row-sum via MFMA on the SAME stored-P fragment (exact).
      const bf16x8 pa = *(const bf16x8*)&Ps[m * 32 + ((q ^ vsw) * 8)];
      __builtin_amdgcn_s_setprio(1);
      lacc[it] = mfma16(pa, vones, lacc[it]);
#pragma unroll
      for (int dt = 0; dt < 4; ++dt) {
        const bf16x8 va = *(const bf16x8*)&Vs[p][(dt * 16 + m) * 32 + ((q ^ vsw) * 8)];
        o[it][dt] = mfma16(pa, va, o[it][dt]);
      }
      __builtin_amdgcn_s_setprio(0);
    }
    __syncthreads();  // Ks/Vs[p] reads done; prefetch (p^1) drained
  }

  // ---- epilogue: lacc already in o's lane layout (row = q*4+r) ----
  const int colb = h * 64;
#pragma unroll
  for (int it = 0; it < 2; ++it) {
    f32x4 lr;
#pragma unroll
    for (int r = 0; r < 4; ++r) lr[r] = 1.0f / lacc[it][r];
#pragma unroll
    for (int dt = 0; dt < 4; ++dt)
#pragma unroll
      for (int r = 0; r < 4; ++r) {
        const int row = i0w + it * 16 + q * 4 + r;
        const size_t addr = ((size_t)b * 512 + row) * 512 + colb + dt * 16 + m;
        const float gate = bf2f(G[addr]);
        G[addr] = f2bf(o[it][dt][r] * lr[r] * gate);
      }
  }
}

// ---------------------------------------------------------------------------
// GEMM3: out = OG[32768,512] @ Wo + bo   (B^T = WoT[256][512]); fp32 output.
// 64x128 tiles, grid (2, 512) -> 4 blocks/CU. Swapped MFMA -> f32x4 stores.
// (Frozen.)
// ---------------------------------------------------------------------------
__global__ __launch_bounds__(256, 2) void gemm_og(
    const short* __restrict__ A, const short* __restrict__ Bt,
    const float* __restrict__ bo, float* __restrict__ out)
{
  __shared__ __align__(16) short As[64 * 32];
  __shared__ __align__(16) short Bs[128 * 32];
  const int tid = threadIdx.x;
  const int w = tid >> 6, lane = tid & 63;
  const int m = lane & 15, q = lane >> 4;
  const int n0 = blockIdx.x * 128, m0 = blockIdx.y * 64;
  const int ric = lane >> 2, cslot = lane & 3;
  const int csw = cslot ^ ((ric >> 1) & 3);
  const int wr = (w >> 1) * 32, wc = (w & 1) * 64;
  const int rsw = (m >> 1) & 3;
  f32x4 acc[2][4] = {};
  for (int k0 = 0; k0 < INNER_; k0 += 32) {
    __syncthreads();
    // As: 64 rows, 1 cp16/thread (wave w stages rows w*16..w*16+15)
    cp16(A + (size_t)(m0 + w * 16 + ric) * INNER_ + (k0 + csw * 8), &As[w * 16 * 32]);
    // Bs: 128 rows, 2 cp16/thread
#pragma unroll
    for (int s = 0; s < 2; ++s) {
      const int rr = w * 32 + s * 16;
      cp16(Bt + (size_t)(n0 + rr + ric) * INNER_ + (k0 + csw * 8), &Bs[rr * 32]);
    }
    __syncthreads();
    bf16x8 af[2], bfv[4];
#pragma unroll
    for (int t = 0; t < 2; ++t)
      af[t]  = *(const bf16x8*)&As[(wr + t * 16 + m) * 32 + ((q ^ rsw) * 8)];
#pragma unroll
    for (int t = 0; t < 4; ++t)
      bfv[t] = *(const bf16x8*)&Bs[(wc + t * 16 + m) * 32 + ((q ^ rsw) * 8)];
#pragma unroll
    for (int ti = 0; ti < 2; ++ti)
#pragma unroll
      for (int tj = 0; tj < 4; ++tj)
        acc[ti][tj] = mfma16(bfv[tj], af[ti], acc[ti][tj]);   // transposed C
  }
#pragma unroll
  for (int ti = 0; ti < 2; ++ti) {
    const int row = m0 + wr + ti * 16 + m;       // one output row per lane
#pragma unroll
    for (int tj = 0; tj < 4; ++tj) {
      const int c0 = n0 + wc + tj * 16 + q * 4;  // 4 consecutive out-columns
      const f32x4 bo4 = *(const f32x4*)&bo[c0];
      f32x4 v;
#pragma unroll
      for (int r = 0; r < 4; ++r) v[r] = acc[ti][tj][r] + bo4[r];
      *(f32x4*)&out[(size_t)row * 256 + c0] = v;
    }
  }
}

// ---------------------------------------------------------------------------
extern "C" void kernel_launch(void* const* d_in, const int* in_sizes, int n_in,
                              void* d_out, int out_size, void* d_ws, size_t ws_size,
                              hipStream_t stream)
{
  (void)in_sizes; (void)n_in; (void)out_size; (void)ws_size;
  const float* x    = (const float*)d_in[0];
  const int*   mask = (const int*)d_in[1];
  const float* bias = (const float*)d_in[2];
  const float* Wq   = (const float*)d_in[3];
  const float* Wkv  = (const float*)d_in[4];
  const float* Wo   = (const float*)d_in[5];
  const float* bo   = (const float*)d_in[6];
  const float* Wg   = (const float*)d_in[7];
  const float* bg   = (const float*)d_in[8];
  float* out = (float*)d_out;

  char* ws = (char*)d_ws;
  size_t off = 0;
  short* Wt1   = (short*)(ws + off); off += (size_t)2048 * 256 * 2;         // 1.0 MiB
  short* WoT   = (short*)(ws + off); off += (size_t)256 * 512 * 2;          // 0.25 MiB
  short* xb    = (short*)(ws + off); off += (size_t)32768 * 256 * 2;        // 16 MiB
  short* Qb    = (short*)(ws + off); off += (size_t)B_ * H_ * N_ * DH_ * 2; // 32 MiB
  short* Kb    = (short*)(ws + off); off += (size_t)B_ * H_ * N_ * DH_ * 2; // 32 MiB
  short* Vt    = (short*)(ws + off); off += (size_t)B_ * H_ * DH_ * N_ * 2; // 32 MiB
  short* G     = (short*)(ws + off); off += (size_t)B_ * N_ * INNER_ * 2;   // 32 MiB
  float* biasS = (float*)(ws + off); off += (size_t)H_ * N_ * N_ * 4;       // 8 MiB
  float* maskF = (float*)(ws + off); off += (size_t)B_ * N_ * 4;            // 128 KiB

  prep_k<<<(PREP_TOT + 255) / 256, 256, 0, stream>>>(x, Wq, Wkv, Wg, Wo, bias, mask,
                                                     Wt1, WoT, xb, biasS, maskF);
  gemm_qkvg<<<dim3(16, 256), 256, 0, stream>>>(xb, Wt1, bg, Qb, Kb, Vt, G);
  attn_k<<<dim3(8, 4, 64), 256, 0, stream>>>(Qb, Kb, Vt, biasS, maskF, G);
  gemm_og<<<dim3(2, 512), 256, 0, stream>>>(G, WoT, bo, out);
}

// Round 9
// 297.158 us; speedup vs baseline: 1.0410x; 1.0410x over previous
//
#include <hip/hip_runtime.h>
#include <stdint.h>

// Problem constants
#define B_    64
#define N_    512
#define DIM_  256
#define H_    8
#define DH_   64
#define INNER_ 512

typedef __attribute__((ext_vector_type(8))) short bf16x8;
typedef __attribute__((ext_vector_type(4))) float f32x4;
typedef __attribute__((ext_vector_type(4))) short s16x4;

typedef const __attribute__((address_space(1))) void* gas_ptr;
typedef __attribute__((address_space(3))) void* las_ptr;

__device__ __forceinline__ short f2bf(float f) {
  unsigned int u = __float_as_uint(f);
  u += 0x7fffu + ((u >> 16) & 1u);          // RNE
  return (short)(u >> 16);
}
__device__ __forceinline__ float bf2f(short s) {
  return __uint_as_float(((unsigned int)(unsigned short)s) << 16);
}
__device__ __forceinline__ void cp16(const void* g, void* l) {
  __builtin_amdgcn_global_load_lds((gas_ptr)g, (las_ptr)l, 16, 0, 0);
}
__device__ __forceinline__ f32x4 mfma16(bf16x8 a, bf16x8 b, f32x4 c) {
  return __builtin_amdgcn_mfma_f32_16x16x32_bf16(a, b, c, 0, 0, 0);
}

// ---------------------------------------------------------------------------
// Prep: fp32 -> bf16 edge conversions (+ scaled bias copy, float mask).
// x-copy and bias-copy regions vectorized x4 (f32x4 loads, s16x4/f32x4
// stores) -- they are 94% of the elements. Wt1/WoT/mask stay scalar.
// ---------------------------------------------------------------------------
#define PREP_WT1  (2048 * 256)
#define PREP_WOT  (256 * 512)
#define PREP_X    (32768 * 256)
#define PREP_BIAS (8 * 512 * 512)
#define PREP_MASK (64 * 512)
#define VEC_X     (PREP_X / 4)
#define VEC_BIAS  (PREP_BIAS / 4)
#define PREP_NEWTOT (VEC_X + VEC_BIAS + PREP_WT1 + PREP_WOT + PREP_MASK)

__global__ void prep_k(const float* __restrict__ x,
                       const float* __restrict__ Wq, const float* __restrict__ Wkv,
                       const float* __restrict__ Wg, const float* __restrict__ Wo,
                       const float* __restrict__ bias, const int* __restrict__ mask,
                       short* __restrict__ Wt1, short* __restrict__ WoT,
                       short* __restrict__ xb, float* __restrict__ biasS,
                       float* __restrict__ maskF)
{
  const int idx = blockIdx.x * 256 + threadIdx.x;
  if (idx < VEC_X) {
    const int j = idx * 4;
    const f32x4 v = *(const f32x4*)&x[j];
    s16x4 st;
#pragma unroll
    for (int r = 0; r < 4; ++r) st[r] = f2bf(v[r]);
    *(s16x4*)&xb[j] = st;
  } else if (idx < VEC_X + VEC_BIAS) {
    const int j = (idx - VEC_X) * 4;
    f32x4 v = *(const f32x4*)&bias[j];
#pragma unroll
    for (int r = 0; r < 4; ++r) v[r] *= 1.4426950408889634f;
    *(f32x4*)&biasS[j] = v;
  } else if (idx < VEC_X + VEC_BIAS + PREP_WT1) {
    const int j = idx - (VEC_X + VEC_BIAS);
    const int n = j >> 8, k = j & 255;
    float v;
    if (n < 512)        v = Wq[k * 512 + n];
    else if (n < 1536)  v = Wkv[k * 1024 + (n - 512)];   // K cols then V cols
    else                v = Wg[k * 512 + (n - 1536)];
    Wt1[j] = f2bf(v);
  } else if (idx < VEC_X + VEC_BIAS + PREP_WT1 + PREP_WOT) {
    const int j = idx - (VEC_X + VEC_BIAS + PREP_WT1);
    const int n = j >> 9, k = j & 511;
    WoT[j] = f2bf(Wo[k * 256 + n]);
  } else if (idx < PREP_NEWTOT) {
    const int j = idx - (VEC_X + VEC_BIAS + PREP_WT1 + PREP_WOT);
    maskF[j] = mask[j] ? 1.0f : 0.0f;
  }
}

// ---------------------------------------------------------------------------
// GEMM1: C = xb[32768,256] @ Wt1^T  (N=2048 fused Q|K|V|G), all bf16.
// BK=64 barrier interval -- stage TWO BK=32 tile pairs (As[2]/Bs[2],
// 32KB LDS), then compute both sub-steps before the next barrier. Halves
// barrier count (16 -> 8) at identical register footprint and identical
// swizzle geometry. Epilogue unchanged (transposed-C s16x4 stores).
// ---------------------------------------------------------------------------
__global__ __launch_bounds__(256, 2) void gemm_qkvg(
    const short* __restrict__ X, const short* __restrict__ Wt,
    const float* __restrict__ bg,
    short* __restrict__ Q, short* __restrict__ Kb,
    short* __restrict__ Vt, short* __restrict__ G)
{
  __shared__ __align__(16) short As[2][128 * 32];
  __shared__ __align__(16) short Bs[2][128 * 32];
  const int tid = threadIdx.x;
  const int w = tid >> 6, lane = tid & 63;
  const int m = lane & 15, q = lane >> 4;
  const int n0 = blockIdx.x * 128, m0 = blockIdx.y * 128;
  const int region = blockIdx.x >> 2;           // 0=Q 1=K 2=V 3=G
  const bool vreg = (region == 2);
  const int ric = lane >> 2, cslot = lane & 3;
  const int csw = cslot ^ ((ric >> 1) & 3);
  const int wr = (w >> 1) * 64, wc = (w & 1) * 64;
  const int rsw = (m >> 1) & 3;
  f32x4 acc[4][4] = {};
  for (int k0 = 0; k0 < DIM_; k0 += 64) {
    __syncthreads();
#pragma unroll
    for (int kh = 0; kh < 2; ++kh) {
      const int kk = k0 + kh * 32;
#pragma unroll
      for (int s = 0; s < 2; ++s) {
        const int rr = w * 32 + s * 16;
        cp16(X  + (size_t)(m0 + rr + ric) * DIM_ + (kk + csw * 8), &As[kh][rr * 32]);
        cp16(Wt + (size_t)(n0 + rr + ric) * DIM_ + (kk + csw * 8), &Bs[kh][rr * 32]);
      }
    }
    __syncthreads();
#pragma unroll
    for (int kh = 0; kh < 2; ++kh) {
      bf16x8 af[4], bfv[4];
#pragma unroll
      for (int t = 0; t < 4; ++t) {
        af[t]  = *(const bf16x8*)&As[kh][(wr + t * 16 + m) * 32 + ((q ^ rsw) * 8)];
        bfv[t] = *(const bf16x8*)&Bs[kh][(wc + t * 16 + m) * 32 + ((q ^ rsw) * 8)];
      }
      if (vreg) {
#pragma unroll
        for (int ti = 0; ti < 4; ++ti)
#pragma unroll
          for (int tj = 0; tj < 4; ++tj)
            acc[ti][tj] = mfma16(af[ti], bfv[tj], acc[ti][tj]);
      } else {
#pragma unroll
        for (int ti = 0; ti < 4; ++ti)
#pragma unroll
          for (int tj = 0; tj < 4; ++tj)
            acc[ti][tj] = mfma16(bfv[tj], af[ti], acc[ti][tj]);  // transposed C
      }
    }
  }
  if (vreg) {                                    // V -> transposed [B,H,DH,N]
    const int cb = (n0 & 511) + wc;
#pragma unroll
    for (int ti = 0; ti < 4; ++ti) {
      const int mgb = m0 + wr + ti * 16 + q * 4;
      const int b = mgb >> 9, n = mgb & 511;
#pragma unroll
      for (int tj = 0; tj < 4; ++tj) {
        const int c = cb + tj * 16 + m;
        const int h = c >> 6, d = c & 63;
        s16x4 st;
#pragma unroll
        for (int r = 0; r < 4; ++r) st[r] = f2bf(acc[ti][tj][r]);
        *(s16x4*)&Vt[((size_t)(b * 8 + h) * 64 + d) * 512 + n] = st;
      }
    }
  } else {                                       // Q / K / G: transposed C
#pragma unroll
    for (int ti = 0; ti < 4; ++ti) {
      const int xrow = m0 + wr + ti * 16 + m;    // one x-row per lane
      const int b = xrow >> 9, n = xrow & 511;
#pragma unroll
      for (int tj = 0; tj < 4; ++tj) {
        const int cvec = (n0 & 511) + wc + tj * 16 + q * 4;  // 4 consecutive cols
        if (region == 3) {                       // gates = x@Wg + bg
          const f32x4 bg4 = *(const f32x4*)&bg[cvec];
          s16x4 st;
#pragma unroll
          for (int r = 0; r < 4; ++r) st[r] = f2bf(acc[ti][tj][r] + bg4[r]);
          *(s16x4*)&G[(size_t)xrow * 512 + cvec] = st;
        } else {
          const int h = cvec >> 6, d0 = cvec & 63;
          s16x4 st;
#pragma unroll
          for (int r = 0; r < 4; ++r) st[r] = f2bf(acc[ti][tj][r]);
          short* dst = (region == 0) ? Q : Kb;
          *(s16x4*)&dst[((size_t)(b * 8 + h) * 512 + n) * 64 + d0] = st;
        }
      }
    }
  }
}

// ---------------------------------------------------------------------------
// Attention (FROZEN at R7 state: KVBLK=32, 20KB LDS, l via MFMA-ones,
// vsw swizzle, setprio, (h,iq,b) grid). ~103 us, structural plateau.
// ---------------------------------------------------------------------------
__global__ __launch_bounds__(256, 4) void attn_k(
    const short* __restrict__ Q, const short* __restrict__ K,
    const short* __restrict__ Vt, const float* __restrict__ biasS,
    const float* __restrict__ maskF, short* __restrict__ G)
{
  __shared__ __align__(16) short Ks[2][32 * 64];   // [j][d], xor-swizzled by j&7
  __shared__ __align__(16) short Vs[2][64 * 32];   // [d][j], slot-xor (d^d>>2)&3
  __shared__ __align__(16) short Pall[4][16 * 32]; // per-wave, slot-xor (i^i>>2)&3
  const int tid = threadIdx.x;
  const int w = tid >> 6, lane = tid & 63;
  const int m = lane & 15, q = lane >> 4;
  const int m7 = m & 7;
  const int vsw = (m ^ (m >> 2)) & 3;              // bank-spread swizzle, 64B rows
  const int h = blockIdx.x, iq = blockIdx.y, b = blockIdx.z;
  const int i0w = iq * 128 + w * 32;               // this wave's first Q row
  const size_t bh = (size_t)b * 8 + h;
  const short* Qp = Q + (bh * 512 + i0w) * 64;
  const short* Kp = K + bh * 512 * 64;
  const short* Vp = Vt + bh * 64 * 512;
  const float* mkp = maskF + b * 512;
  short* Ps = Pall[w];

  const int srow = lane >> 3;                      // 0..7
  const int gchunk = (lane & 7) ^ srow;            // global d-chunk (xor by row&7)
  const int vrow = lane >> 2;                      // 0..15
  const int gchunkV = (lane & 3) ^ ((vrow ^ (vrow >> 2)) & 3);

  bf16x8 vones;
#pragma unroll
  for (int r = 0; r < 8; ++r) vones[r] = (short)0x3F80;

  bf16x8 qf[2][2];
#pragma unroll
  for (int it = 0; it < 2; ++it) {
    qf[it][0] = *(const bf16x8*)&Qp[(it * 16 + m) * 64 + q * 8];
    qf[it][1] = *(const bf16x8*)&Qp[(it * 16 + m) * 64 + 32 + q * 8];
  }
  float miF[2];
#pragma unroll
  for (int it = 0; it < 2; ++it) miF[it] = mkp[i0w + it * 16 + m];

  cp16(Kp + (size_t)(w * 8 + srow) * 64 + gchunk * 8, &Ks[0][w * 8 * 64]);
  cp16(Vp + (size_t)(w * 16 + vrow) * 512 + gchunkV * 8, &Vs[0][w * 16 * 32]);

  f32x4 o[2][4] = {};
  f32x4 lacc[2] = {};                              // l in o-layout (row = q*4+r)
  __syncthreads();                                 // chunk 0 staged

  const float SCL = 0.125f * 1.4426950408889634f;  // scale * log2(e)
  for (int c = 0; c < 16; ++c) {
    const int p = c & 1;
    if (c < 15) {                                  // prefetch next chunk
      const int jn = (c + 1) * 32;
      cp16(Kp + (size_t)(jn + w * 8 + srow) * 64 + gchunk * 8, &Ks[p ^ 1][w * 8 * 64]);
      cp16(Vp + (size_t)(w * 16 + vrow) * 512 + jn + gchunkV * 8, &Vs[p ^ 1][w * 16 * 32]);
    }
    f32x4 mjf[2];
#pragma unroll
    for (int jt = 0; jt < 2; ++jt)
      mjf[jt] = *(const f32x4*)&mkp[c * 32 + jt * 16 + q * 4];

    f32x4 s[2][2];
    __builtin_amdgcn_s_setprio(1);
#pragma unroll
    for (int jt = 0; jt < 2; ++jt) {
      const bf16x8 ka = *(const bf16x8*)&Ks[p][(jt * 16 + m) * 64 + ((q ^ m7) * 8)];
      const bf16x8 kb = *(const bf16x8*)&Ks[p][(jt * 16 + m) * 64 + (((4 + q) ^ m7) * 8)];
#pragma unroll
      for (int it = 0; it < 2; ++it) {
        f32x4 a = {};
        a = mfma16(ka, qf[it][0], a);
        s[it][jt] = mfma16(kb, qf[it][1], a);
      }
    }
    __builtin_amdgcn_s_setprio(0);
#pragma unroll
    for (int it = 0; it < 2; ++it) {
      const float* bp = biasS + ((size_t)h * 512 + i0w + it * 16 + m) * 512 + c * 32;
      f32x4 bv[2];
#pragma unroll
      for (int jt = 0; jt < 2; ++jt)
        bv[jt] = *(const f32x4*)&bp[jt * 16 + q * 4];
#pragma unroll
      for (int jt = 0; jt < 2; ++jt) {
        s16x4 st;
#pragma unroll
        for (int r = 0; r < 4; ++r) {
          const float v = fmaf(s[it][jt][r], SCL, bv[jt][r]);
          float e = exp2f(v) * mjf[jt][r];
          e = (miF[it] != 0.0f) ? e : 1.0f;        // fully-masked row -> uniform
          st[r] = (short)(__float_as_uint(e) >> 16);  // trunc pack
        }
        *(s16x4*)&Ps[m * 32 + (((jt * 2 + (q >> 1)) ^ vsw) * 8) + (q & 1) * 4] = st;
      }
      const bf16x8 pa = *(const bf16x8*)&Ps[m * 32 + ((q ^ vsw) * 8)];
      __builtin_amdgcn_s_setprio(1);
      lacc[it] = mfma16(pa, vones, lacc[it]);
#pragma unroll
      for (int dt = 0; dt < 4; ++dt) {
        const bf16x8 va = *(const bf16x8*)&Vs[p][(dt * 16 + m) * 32 + ((q ^ vsw) * 8)];
        o[it][dt] = mfma16(pa, va, o[it][dt]);
      }
      __builtin_amdgcn_s_setprio(0);
    }
    __syncthreads();  // Ks/Vs[p] reads done; prefetch (p^1) drained
  }

  const int colb = h * 64;
#pragma unroll
  for (int it = 0; it < 2; ++it) {
    f32x4 lr;
#pragma unroll
    for (int r = 0; r < 4; ++r) lr[r] = 1.0f / lacc[it][r];
#pragma unroll
    for (int dt = 0; dt < 4; ++dt)
#pragma unroll
      for (int r = 0; r < 4; ++r) {
        const int row = i0w + it * 16 + q * 4 + r;
        const size_t addr = ((size_t)b * 512 + row) * 512 + colb + dt * 16 + m;
        const float gate = bf2f(G[addr]);
        G[addr] = f2bf(o[it][dt][r] * lr[r] * gate);
      }
  }
}

// ---------------------------------------------------------------------------
// GEMM3: out = OG[32768,512] @ Wo + bo   (B^T = WoT[256][512]); fp32 output.
// BK=64 barrier interval (As[2]/Bs[2], 24KB LDS, 8 barriers instead of
// 16). 64x128 tiles, grid (2, 512). Swapped MFMA -> f32x4 stores.
// ---------------------------------------------------------------------------
__global__ __launch_bounds__(256, 2) void gemm_og(
    const short* __restrict__ A, const short* __restrict__ Bt,
    const float* __restrict__ bo, float* __restrict__ out)
{
  __shared__ __align__(16) short As[2][64 * 32];
  __shared__ __align__(16) short Bs[2][128 * 32];
  const int tid = threadIdx.x;
  const int w = tid >> 6, lane = tid & 63;
  const int m = lane & 15, q = lane >> 4;
  const int n0 = blockIdx.x * 128, m0 = blockIdx.y * 64;
  const int ric = lane >> 2, cslot = lane & 3;
  const int csw = cslot ^ ((ric >> 1) & 3);
  const int wr = (w >> 1) * 32, wc = (w & 1) * 64;
  const int rsw = (m >> 1) & 3;
  f32x4 acc[2][4] = {};
  for (int k0 = 0; k0 < INNER_; k0 += 64) {
    __syncthreads();
#pragma unroll
    for (int kh = 0; kh < 2; ++kh) {
      const int kk = k0 + kh * 32;
      cp16(A + (size_t)(m0 + w * 16 + ric) * INNER_ + (kk + csw * 8), &As[kh][w * 16 * 32]);
#pragma unroll
      for (int s = 0; s < 2; ++s) {
        const int rr = w * 32 + s * 16;
        cp16(Bt + (size_t)(n0 + rr + ric) * INNER_ + (kk + csw * 8), &Bs[kh][rr * 32]);
      }
    }
    __syncthreads();
#pragma unroll
    for (int kh = 0; kh < 2; ++kh) {
      bf16x8 af[2], bfv[4];
#pragma unroll
      for (int t = 0; t < 2; ++t)
        af[t]  = *(const bf16x8*)&As[kh][(wr + t * 16 + m) * 32 + ((q ^ rsw) * 8)];
#pragma unroll
      for (int t = 0; t < 4; ++t)
        bfv[t] = *(const bf16x8*)&Bs[kh][(wc + t * 16 + m) * 32 + ((q ^ rsw) * 8)];
#pragma unroll
      for (int ti = 0; ti < 2; ++ti)
#pragma unroll
        for (int tj = 0; tj < 4; ++tj)
          acc[ti][tj] = mfma16(bfv[tj], af[ti], acc[ti][tj]);   // transposed C
    }
  }
#pragma unroll
  for (int ti = 0; ti < 2; ++ti) {
    const int row = m0 + wr + ti * 16 + m;       // one output row per lane
#pragma unroll
    for (int tj = 0; tj < 4; ++tj) {
      const int c0 = n0 + wc + tj * 16 + q * 4;  // 4 consecutive out-columns
      const f32x4 bo4 = *(const f32x4*)&bo[c0];
      f32x4 v;
#pragma unroll
      for (int r = 0; r < 4; ++r) v[r] = acc[ti][tj][r] + bo4[r];
      *(f32x4*)&out[(size_t)row * 256 + c0] = v;
    }
  }
}

// ---------------------------------------------------------------------------
extern "C" void kernel_launch(void* const* d_in, const int* in_sizes, int n_in,
                              void* d_out, int out_size, void* d_ws, size_t ws_size,
                              hipStream_t stream)
{
  (void)in_sizes; (void)n_in; (void)out_size; (void)ws_size;
  const float* x    = (const float*)d_in[0];
  const int*   mask = (const int*)d_in[1];
  const float* bias = (const float*)d_in[2];
  const float* Wq   = (const float*)d_in[3];
  const float* Wkv  = (const float*)d_in[4];
  const float* Wo   = (const float*)d_in[5];
  const float* bo   = (const float*)d_in[6];
  const float* Wg   = (const float*)d_in[7];
  const float* bg   = (const float*)d_in[8];
  float* out = (float*)d_out;

  char* ws = (char*)d_ws;
  size_t off = 0;
  short* Wt1   = (short*)(ws + off); off += (size_t)2048 * 256 * 2;         // 1.0 MiB
  short* WoT   = (short*)(ws + off); off += (size_t)256 * 512 * 2;          // 0.25 MiB
  short* xb    = (short*)(ws + off); off += (size_t)32768 * 256 * 2;        // 16 MiB
  short* Qb    = (short*)(ws + off); off += (size_t)B_ * H_ * N_ * DH_ * 2; // 32 MiB
  short* Kb    = (short*)(ws + off); off += (size_t)B_ * H_ * N_ * DH_ * 2; // 32 MiB
  short* Vt    = (short*)(ws + off); off += (size_t)B_ * H_ * DH_ * N_ * 2; // 32 MiB
  short* G     = (short*)(ws + off); off += (size_t)B_ * N_ * INNER_ * 2;   // 32 MiB
  float* biasS = (float*)(ws + off); off += (size_t)H_ * N_ * N_ * 4;       // 8 MiB
  float* maskF = (float*)(ws + off); off += (size_t)B_ * N_ * 4;            // 128 KiB

  prep_k<<<(PREP_NEWTOT + 255) / 256, 256, 0, stream>>>(x, Wq, Wkv, Wg, Wo, bias, mask,
                                                        Wt1, WoT, xb, biasS, maskF);
  gemm_qkvg<<<dim3(16, 256), 256, 0, stream>>>(xb, Wt1, bg, Qb, Kb, Vt, G);
  attn_k<<<dim3(8, 4, 64), 256, 0, stream>>>(Qb, Kb, Vt, biasS, maskF, G);
  gemm_og<<<dim3(2, 512), 256, 0, stream>>>(G, WoT, bo, out);
}

// Round 10
// 276.383 us; speedup vs baseline: 1.1193x; 1.0752x over previous
//
#include <hip/hip_runtime.h>
#include <stdint.h>

// Problem constants
#define B_    64
#define N_    512
#define DIM_  256
#define H_    8
#define DH_   64
#define INNER_ 512

typedef __attribute__((ext_vector_type(8))) short bf16x8;
typedef __attribute__((ext_vector_type(4))) float f32x4;
typedef __attribute__((ext_vector_type(4))) short s16x4;

typedef const __attribute__((address_space(1))) void* gas_ptr;
typedef __attribute__((address_space(3))) void* las_ptr;

__device__ __forceinline__ short f2bf(float f) {
  unsigned int u = __float_as_uint(f);
  u += 0x7fffu + ((u >> 16) & 1u);          // RNE
  return (short)(u >> 16);
}
__device__ __forceinline__ float bf2f(short s) {
  return __uint_as_float(((unsigned int)(unsigned short)s) << 16);
}
__device__ __forceinline__ void cp16(const void* g, void* l) {
  __builtin_amdgcn_global_load_lds((gas_ptr)g, (las_ptr)l, 16, 0, 0);
}
__device__ __forceinline__ f32x4 mfma16(bf16x8 a, bf16x8 b, f32x4 c) {
  return __builtin_amdgcn_mfma_f32_16x16x32_bf16(a, b, c, 0, 0, 0);
}

// ---------------------------------------------------------------------------
// Prep: fp32 -> bf16 edge conversions (+ scaled bias copy, float mask).
// x/bias regions vectorized x4. (Frozen.)
// ---------------------------------------------------------------------------
#define PREP_WT1  (2048 * 256)
#define PREP_WOT  (256 * 512)
#define PREP_X    (32768 * 256)
#define PREP_BIAS (8 * 512 * 512)
#define PREP_MASK (64 * 512)
#define VEC_X     (PREP_X / 4)
#define VEC_BIAS  (PREP_BIAS / 4)
#define PREP_NEWTOT (VEC_X + VEC_BIAS + PREP_WT1 + PREP_WOT + PREP_MASK)

__global__ void prep_k(const float* __restrict__ x,
                       const float* __restrict__ Wq, const float* __restrict__ Wkv,
                       const float* __restrict__ Wg, const float* __restrict__ Wo,
                       const float* __restrict__ bias, const int* __restrict__ mask,
                       short* __restrict__ Wt1, short* __restrict__ WoT,
                       short* __restrict__ xb, float* __restrict__ biasS,
                       float* __restrict__ maskF)
{
  const int idx = blockIdx.x * 256 + threadIdx.x;
  if (idx < VEC_X) {
    const int j = idx * 4;
    const f32x4 v = *(const f32x4*)&x[j];
    s16x4 st;
#pragma unroll
    for (int r = 0; r < 4; ++r) st[r] = f2bf(v[r]);
    *(s16x4*)&xb[j] = st;
  } else if (idx < VEC_X + VEC_BIAS) {
    const int j = (idx - VEC_X) * 4;
    f32x4 v = *(const f32x4*)&bias[j];
#pragma unroll
    for (int r = 0; r < 4; ++r) v[r] *= 1.4426950408889634f;
    *(f32x4*)&biasS[j] = v;
  } else if (idx < VEC_X + VEC_BIAS + PREP_WT1) {
    const int j = idx - (VEC_X + VEC_BIAS);
    const int n = j >> 8, k = j & 255;
    float v;
    if (n < 512)        v = Wq[k * 512 + n];
    else if (n < 1536)  v = Wkv[k * 1024 + (n - 512)];   // K cols then V cols
    else                v = Wg[k * 512 + (n - 1536)];
    Wt1[j] = f2bf(v);
  } else if (idx < VEC_X + VEC_BIAS + PREP_WT1 + PREP_WOT) {
    const int j = idx - (VEC_X + VEC_BIAS + PREP_WT1);
    const int n = j >> 9, k = j & 511;
    WoT[j] = f2bf(Wo[k * 256 + n]);
  } else if (idx < PREP_NEWTOT) {
    const int j = idx - (VEC_X + VEC_BIAS + PREP_WT1 + PREP_WOT);
    maskF[j] = mask[j] ? 1.0f : 0.0f;
  }
}

// ---------------------------------------------------------------------------
// GEMM1: C = xb[32768,256] @ Wt1^T  (N=2048 fused Q|K|V|G), all bf16.
// BK=64 barrier interval (As/Bs double tiles, 32KB LDS).
// NEW: LDS-staged coalesced epilogue. Old stores were 8B-scattered (V:
// 1KB-stride s16x4 = ~8x HBM write amplification) / 32B segments (Q,K,G).
// Now: fragments -> swizzled 128x128 bf16 LDS tile (reusing the 32KB
// staging union) -> each thread streams 8x16B chunks, 128B-contiguous runs
// in all four regions. V is written TRANSPOSED into LDS (normal-orientation
// fragment = contiguous s16x4 LDS writes), read out along n.
// Swizzle: 8B slot index ^ (row&15)<<1 -> ~2-way banks both phases.
// ---------------------------------------------------------------------------
__global__ __launch_bounds__(256, 2) void gemm_qkvg(
    const short* __restrict__ X, const short* __restrict__ Wt,
    const float* __restrict__ bg,
    short* __restrict__ Q, short* __restrict__ Kb,
    short* __restrict__ Vt, short* __restrict__ G)
{
  __shared__ __align__(16) short SM[16384];        // As[2]|Bs[2] staging, reused
  short* As0 = &SM[0];                             //   as 128x128 epilogue tile
  short* As1 = &SM[4096];
  short* Bs0 = &SM[8192];
  short* Bs1 = &SM[12288];
  const int tid = threadIdx.x;
  const int w = tid >> 6, lane = tid & 63;
  const int m = lane & 15, q = lane >> 4;
  const int n0 = blockIdx.x * 128, m0 = blockIdx.y * 128;
  const int region = blockIdx.x >> 2;           // 0=Q 1=K 2=V 3=G
  const bool vreg = (region == 2);
  const int ric = lane >> 2, cslot = lane & 3;
  const int csw = cslot ^ ((ric >> 1) & 3);
  const int wr = (w >> 1) * 64, wc = (w & 1) * 64;
  const int rsw = (m >> 1) & 3;
  f32x4 acc[4][4] = {};
  for (int k0 = 0; k0 < DIM_; k0 += 64) {
    __syncthreads();
#pragma unroll
    for (int s = 0; s < 2; ++s) {
      const int rr = w * 32 + s * 16;
      cp16(X  + (size_t)(m0 + rr + ric) * DIM_ + (k0 + csw * 8),      &As0[rr * 32]);
      cp16(Wt + (size_t)(n0 + rr + ric) * DIM_ + (k0 + csw * 8),      &Bs0[rr * 32]);
      cp16(X  + (size_t)(m0 + rr + ric) * DIM_ + (k0 + 32 + csw * 8), &As1[rr * 32]);
      cp16(Wt + (size_t)(n0 + rr + ric) * DIM_ + (k0 + 32 + csw * 8), &Bs1[rr * 32]);
    }
    __syncthreads();
#pragma unroll
    for (int kh = 0; kh < 2; ++kh) {
      const short* Ap = kh ? As1 : As0;
      const short* Bp = kh ? Bs1 : Bs0;
      bf16x8 af[4], bfv[4];
#pragma unroll
      for (int t = 0; t < 4; ++t) {
        af[t]  = *(const bf16x8*)&Ap[(wr + t * 16 + m) * 32 + ((q ^ rsw) * 8)];
        bfv[t] = *(const bf16x8*)&Bp[(wc + t * 16 + m) * 32 + ((q ^ rsw) * 8)];
      }
      if (vreg) {
#pragma unroll
        for (int ti = 0; ti < 4; ++ti)
#pragma unroll
          for (int tj = 0; tj < 4; ++tj)
            acc[ti][tj] = mfma16(af[ti], bfv[tj], acc[ti][tj]);
      } else {
#pragma unroll
        for (int ti = 0; ti < 4; ++ti)
#pragma unroll
          for (int tj = 0; tj < 4; ++tj)
            acc[ti][tj] = mfma16(bfv[tj], af[ti], acc[ti][tj]);  // transposed C
      }
    }
  }

  // ---- LDS-staged coalesced epilogue ----
  __syncthreads();                                 // all As/Bs reads done
  short* Ls = SM;                                  // 128x128 shorts
  const int nb = n0 & 511;
  if (vreg) {
    // normal C: lane has 4 consecutive n-rows for one column c -> store
    // TRANSPOSED Ls[c][n]: contiguous s16x4 along n.
#pragma unroll
    for (int ti = 0; ti < 4; ++ti) {
      const int sl = (wr + ti * 16) / 4 + q;       // n-slot (4-aligned base + q)
#pragma unroll
      for (int tj = 0; tj < 4; ++tj) {
        const int cl = wc + tj * 16 + m;
        s16x4 st;
#pragma unroll
        for (int r = 0; r < 4; ++r) st[r] = f2bf(acc[ti][tj][r]);
        *(s16x4*)&Ls[cl * 128 + ((sl ^ ((cl & 15) << 1)) << 2)] = st;
      }
    }
  } else {
    // transposed C: lane has one row, 4 consecutive cols -> Ls[row][c].
#pragma unroll
    for (int ti = 0; ti < 4; ++ti) {
      const int rl = wr + ti * 16 + m;
#pragma unroll
      for (int tj = 0; tj < 4; ++tj) {
        const int cl = wc + tj * 16 + q * 4;
        f32x4 v = acc[ti][tj];
        if (region == 3) {
          const f32x4 bg4 = *(const f32x4*)&bg[nb + cl];
#pragma unroll
          for (int r = 0; r < 4; ++r) v[r] += bg4[r];
        }
        s16x4 st;
#pragma unroll
        for (int r = 0; r < 4; ++r) st[r] = f2bf(v[r]);
        *(s16x4*)&Ls[rl * 128 + (((cl >> 2) ^ ((rl & 15) << 1)) << 2)] = st;
      }
    }
  }
  __syncthreads();
  const int bblk = m0 >> 9, nbase = m0 & 511;
#pragma unroll
  for (int k = 0; k < 8; ++k) {
    const int ch = k * 256 + tid;
    const int rr = ch >> 4, off = ch & 15;         // rr: row (QKG) / d-col (V)
    const bf16x8 vv =
        *(const bf16x8*)&Ls[rr * 128 + ((((off << 1) ^ ((rr & 15) << 1))) << 2)];
    if (vreg) {                                    // Vt[bh][d][n], 16B along n
      const int cg = nb + rr;
      const int h = cg >> 6, d = cg & 63;
      *(bf16x8*)&Vt[((size_t)(bblk * 8 + h) * 64 + d) * 512 + nbase + off * 8] = vv;
    } else if (region == 3) {                      // G[row][c], 16B along c
      *(bf16x8*)&G[(size_t)(m0 + rr) * 512 + nb + off * 8] = vv;
    } else {                                       // Q/K [bh][n][d], 16B along d
      const int cg = nb + off * 8;
      const int h = cg >> 6, d0 = cg & 63;
      short* dst = (region == 0) ? Q : Kb;
      *(bf16x8*)&dst[((size_t)(bblk * 8 + h) * 512 + nbase + rr) * 64 + d0] = vv;
    }
  }
}

// ---------------------------------------------------------------------------
// Attention (FROZEN at R7 state: KVBLK=32, 20KB LDS, l via MFMA-ones,
// vsw swizzle, setprio, (h,iq,b) grid). ~103 us, structural plateau.
// ---------------------------------------------------------------------------
__global__ __launch_bounds__(256, 4) void attn_k(
    const short* __restrict__ Q, const short* __restrict__ K,
    const short* __restrict__ Vt, const float* __restrict__ biasS,
    const float* __restrict__ maskF, short* __restrict__ G)
{
  __shared__ __align__(16) short Ks[2][32 * 64];   // [j][d], xor-swizzled by j&7
  __shared__ __align__(16) short Vs[2][64 * 32];   // [d][j], slot-xor (d^d>>2)&3
  __shared__ __align__(16) short Pall[4][16 * 32]; // per-wave, slot-xor (i^i>>2)&3
  const int tid = threadIdx.x;
  const int w = tid >> 6, lane = tid & 63;
  const int m = lane & 15, q = lane >> 4;
  const int m7 = m & 7;
  const int vsw = (m ^ (m >> 2)) & 3;              // bank-spread swizzle, 64B rows
  const int h = blockIdx.x, iq = blockIdx.y, b = blockIdx.z;
  const int i0w = iq * 128 + w * 32;               // this wave's first Q row
  const size_t bh = (size_t)b * 8 + h;
  const short* Qp = Q + (bh * 512 + i0w) * 64;
  const short* Kp = K + bh * 512 * 64;
  const short* Vp = Vt + bh * 64 * 512;
  const float* mkp = maskF + b * 512;
  short* Ps = Pall[w];

  const int srow = lane >> 3;                      // 0..7
  const int gchunk = (lane & 7) ^ srow;            // global d-chunk (xor by row&7)
  const int vrow = lane >> 2;                      // 0..15
  const int gchunkV = (lane & 3) ^ ((vrow ^ (vrow >> 2)) & 3);

  bf16x8 vones;
#pragma unroll
  for (int r = 0; r < 8; ++r) vones[r] = (short)0x3F80;

  bf16x8 qf[2][2];
#pragma unroll
  for (int it = 0; it < 2; ++it) {
    qf[it][0] = *(const bf16x8*)&Qp[(it * 16 + m) * 64 + q * 8];
    qf[it][1] = *(const bf16x8*)&Qp[(it * 16 + m) * 64 + 32 + q * 8];
  }
  float miF[2];
#pragma unroll
  for (int it = 0; it < 2; ++it) miF[it] = mkp[i0w + it * 16 + m];

  cp16(Kp + (size_t)(w * 8 + srow) * 64 + gchunk * 8, &Ks[0][w * 8 * 64]);
  cp16(Vp + (size_t)(w * 16 + vrow) * 512 + gchunkV * 8, &Vs[0][w * 16 * 32]);

  f32x4 o[2][4] = {};
  f32x4 lacc[2] = {};                              // l in o-layout (row = q*4+r)
  __syncthreads();                                 // chunk 0 staged

  const float SCL = 0.125f * 1.4426950408889634f;  // scale * log2(e)
  for (int c = 0; c < 16; ++c) {
    const int p = c & 1;
    if (c < 15) {                                  // prefetch next chunk
      const int jn = (c + 1) * 32;
      cp16(Kp + (size_t)(jn + w * 8 + srow) * 64 + gchunk * 8, &Ks[p ^ 1][w * 8 * 64]);
      cp16(Vp + (size_t)(w * 16 + vrow) * 512 + jn + gchunkV * 8, &Vs[p ^ 1][w * 16 * 32]);
    }
    f32x4 mjf[2];
#pragma unroll
    for (int jt = 0; jt < 2; ++jt)
      mjf[jt] = *(const f32x4*)&mkp[c * 32 + jt * 16 + q * 4];

    f32x4 s[2][2];
    __builtin_amdgcn_s_setprio(1);
#pragma unroll
    for (int jt = 0; jt < 2; ++jt) {
      const bf16x8 ka = *(const bf16x8*)&Ks[p][(jt * 16 + m) * 64 + ((q ^ m7) * 8)];
      const bf16x8 kb = *(const bf16x8*)&Ks[p][(jt * 16 + m) * 64 + (((4 + q) ^ m7) * 8)];
#pragma unroll
      for (int it = 0; it < 2; ++it) {
        f32x4 a = {};
        a = mfma16(ka, qf[it][0], a);
        s[it][jt] = mfma16(kb, qf[it][1], a);
      }
    }
    __builtin_amdgcn_s_setprio(0);
#pragma unroll
    for (int it = 0; it < 2; ++it) {
      const float* bp = biasS + ((size_t)h * 512 + i0w + it * 16 + m) * 512 + c * 32;
      f32x4 bv[2];
#pragma unroll
      for (int jt = 0; jt < 2; ++jt)
        bv[jt] = *(const f32x4*)&bp[jt * 16 + q * 4];
#pragma unroll
      for (int jt = 0; jt < 2; ++jt) {
        s16x4 st;
#pragma unroll
        for (int r = 0; r < 4; ++r) {
          const float v = fmaf(s[it][jt][r], SCL, bv[jt][r]);
          float e = exp2f(v) * mjf[jt][r];
          e = (miF[it] != 0.0f) ? e : 1.0f;        // fully-masked row -> uniform
          st[r] = (short)(__float_as_uint(e) >> 16);  // trunc pack
        }
        *(s16x4*)&Ps[m * 32 + (((jt * 2 + (q >> 1)) ^ vsw) * 8) + (q & 1) * 4] = st;
      }
      const bf16x8 pa = *(const bf16x8*)&Ps[m * 32 + ((q ^ vsw) * 8)];
      __builtin_amdgcn_s_setprio(1);
      lacc[it] = mfma16(pa, vones, lacc[it]);
#pragma unroll
      for (int dt = 0; dt < 4; ++dt) {
        const bf16x8 va = *(const bf16x8*)&Vs[p][(dt * 16 + m) * 32 + ((q ^ vsw) * 8)];
        o[it][dt] = mfma16(pa, va, o[it][dt]);
      }
      __builtin_amdgcn_s_setprio(0);
    }
    __syncthreads();  // Ks/Vs[p] reads done; prefetch (p^1) drained
  }

  const int colb = h * 64;
#pragma unroll
  for (int it = 0; it < 2; ++it) {
    f32x4 lr;
#pragma unroll
    for (int r = 0; r < 4; ++r) lr[r] = 1.0f / lacc[it][r];
#pragma unroll
    for (int dt = 0; dt < 4; ++dt)
#pragma unroll
      for (int r = 0; r < 4; ++r) {
        const int row = i0w + it * 16 + q * 4 + r;
        const size_t addr = ((size_t)b * 512 + row) * 512 + colb + dt * 16 + m;
        const float gate = bf2f(G[addr]);
        G[addr] = f2bf(o[it][dt][r] * lr[r] * gate);
      }
  }
}

// ---------------------------------------------------------------------------
// GEMM3: out = OG[32768,512] @ Wo + bo   (B^T = WoT[256][512]); fp32 output.
// BK=64 barrier interval. 64x128 tiles, grid (2, 512). (Frozen.)
// ---------------------------------------------------------------------------
__global__ __launch_bounds__(256, 2) void gemm_og(
    const short* __restrict__ A, const short* __restrict__ Bt,
    const float* __restrict__ bo, float* __restrict__ out)
{
  __shared__ __align__(16) short As[2][64 * 32];
  __shared__ __align__(16) short Bs[2][128 * 32];
  const int tid = threadIdx.x;
  const int w = tid >> 6, lane = tid & 63;
  const int m = lane & 15, q = lane >> 4;
  const int n0 = blockIdx.x * 128, m0 = blockIdx.y * 64;
  const int ric = lane >> 2, cslot = lane & 3;
  const int csw = cslot ^ ((ric >> 1) & 3);
  const int wr = (w >> 1) * 32, wc = (w & 1) * 64;
  const int rsw = (m >> 1) & 3;
  f32x4 acc[2][4] = {};
  for (int k0 = 0; k0 < INNER_; k0 += 64) {
    __syncthreads();
#pragma unroll
    for (int kh = 0; kh < 2; ++kh) {
      const int kk = k0 + kh * 32;
      cp16(A + (size_t)(m0 + w * 16 + ric) * INNER_ + (kk + csw * 8), &As[kh][w * 16 * 32]);
#pragma unroll
      for (int s = 0; s < 2; ++s) {
        const int rr = w * 32 + s * 16;
        cp16(Bt + (size_t)(n0 + rr + ric) * INNER_ + (kk + csw * 8), &Bs[kh][rr * 32]);
      }
    }
    __syncthreads();
#pragma unroll
    for (int kh = 0; kh < 2; ++kh) {
      bf16x8 af[2], bfv[4];
#pragma unroll
      for (int t = 0; t < 2; ++t)
        af[t]  = *(const bf16x8*)&As[kh][(wr + t * 16 + m) * 32 + ((q ^ rsw) * 8)];
#pragma unroll
      for (int t = 0; t < 4; ++t)
        bfv[t] = *(const bf16x8*)&Bs[kh][(wc + t * 16 + m) * 32 + ((q ^ rsw) * 8)];
#pragma unroll
      for (int ti = 0; ti < 2; ++ti)
#pragma unroll
        for (int tj = 0; tj < 4; ++tj)
          acc[ti][tj] = mfma16(bfv[tj], af[ti], acc[ti][tj]);   // transposed C
    }
  }
#pragma unroll
  for (int ti = 0; ti < 2; ++ti) {
    const int row = m0 + wr + ti * 16 + m;       // one output row per lane
#pragma unroll
    for (int tj = 0; tj < 4; ++tj) {
      const int c0 = n0 + wc + tj * 16 + q * 4;  // 4 consecutive out-columns
      const f32x4 bo4 = *(const f32x4*)&bo[c0];
      f32x4 v;
#pragma unroll
      for (int r = 0; r < 4; ++r) v[r] = acc[ti][tj][r] + bo4[r];
      *(f32x4*)&out[(size_t)row * 256 + c0] = v;
    }
  }
}

// ---------------------------------------------------------------------------
extern "C" void kernel_launch(void* const* d_in, const int* in_sizes, int n_in,
                              void* d_out, int out_size, void* d_ws, size_t ws_size,
                              hipStream_t stream)
{
  (void)in_sizes; (void)n_in; (void)out_size; (void)ws_size;
  const float* x    = (const float*)d_in[0];
  const int*   mask = (const int*)d_in[1];
  const float* bias = (const float*)d_in[2];
  const float* Wq   = (const float*)d_in[3];
  const float* Wkv  = (const float*)d_in[4];
  const float* Wo   = (const float*)d_in[5];
  const float* bo   = (const float*)d_in[6];
  const float* Wg   = (const float*)d_in[7];
  const float* bg   = (const float*)d_in[8];
  float* out = (float*)d_out;

  char* ws = (char*)d_ws;
  size_t off = 0;
  short* Wt1   = (short*)(ws + off); off += (size_t)2048 * 256 * 2;         // 1.0 MiB
  short* WoT   = (short*)(ws + off); off += (size_t)256 * 512 * 2;          // 0.25 MiB
  short* xb    = (short*)(ws + off); off += (size_t)32768 * 256 * 2;        // 16 MiB
  short* Qb    = (short*)(ws + off); off += (size_t)B_ * H_ * N_ * DH_ * 2; // 32 MiB
  short* Kb    = (short*)(ws + off); off += (size_t)B_ * H_ * N_ * DH_ * 2; // 32 MiB
  short* Vt    = (short*)(ws + off); off += (size_t)B_ * H_ * DH_ * N_ * 2; // 32 MiB
  short* G     = (short*)(ws + off); off += (size_t)B_ * N_ * INNER_ * 2;   // 32 MiB
  float* biasS = (float*)(ws + off); off += (size_t)H_ * N_ * N_ * 4;       // 8 MiB
  float* maskF = (float*)(ws + off); off += (size_t)B_ * N_ * 4;            // 128 KiB

  prep_k<<<(PREP_NEWTOT + 255) / 256, 256, 0, stream>>>(x, Wq, Wkv, Wg, Wo, bias, mask,
                                                        Wt1, WoT, xb, biasS, maskF);
  gemm_qkvg<<<dim3(16, 256), 256, 0, stream>>>(xb, Wt1, bg, Qb, Kb, Vt, G);
  attn_k<<<dim3(8, 4, 64), 256, 0, stream>>>(Qb, Kb, Vt, biasS, maskF, G);
  gemm_og<<<dim3(2, 512), 256, 0, stream>>>(G, WoT, bo, out);
}

// Round 11
// 267.224 us; speedup vs baseline: 1.1576x; 1.0343x over previous
//
#include <hip/hip_runtime.h>
#include <stdint.h>

// Problem constants
#define B_    64
#define N_    512
#define DIM_  256
#define H_    8
#define DH_   64
#define INNER_ 512

typedef __attribute__((ext_vector_type(8))) short bf16x8;
typedef __attribute__((ext_vector_type(4))) float f32x4;
typedef __attribute__((ext_vector_type(4))) short s16x4;

typedef const __attribute__((address_space(1))) void* gas_ptr;
typedef __attribute__((address_space(3))) void* las_ptr;

__device__ __forceinline__ short f2bf(float f) {
  unsigned int u = __float_as_uint(f);
  u += 0x7fffu + ((u >> 16) & 1u);          // RNE
  return (short)(u >> 16);
}
__device__ __forceinline__ float bf2f(short s) {
  return __uint_as_float(((unsigned int)(unsigned short)s) << 16);
}
__device__ __forceinline__ void cp16(const void* g, void* l) {
  __builtin_amdgcn_global_load_lds((gas_ptr)g, (las_ptr)l, 16, 0, 0);
}
__device__ __forceinline__ f32x4 mfma16(bf16x8 a, bf16x8 b, f32x4 c) {
  return __builtin_amdgcn_mfma_f32_16x16x32_bf16(a, b, c, 0, 0, 0);
}

// ---------------------------------------------------------------------------
// prep_k: vectorized x->bf16, bias*log2e, mask->float. Weight transposes
// moved to prep_w (they were fully-scattered 4B reads here).
// ---------------------------------------------------------------------------
#define PREP_X    (32768 * 256)
#define PREP_BIAS (8 * 512 * 512)
#define PREP_MASK (64 * 512)
#define VEC_X     (PREP_X / 4)
#define VEC_BIAS  (PREP_BIAS / 4)
#define PREP_KTOT (VEC_X + VEC_BIAS + PREP_MASK)   // 2,654,208 = 10368*256

__global__ void prep_k(const float* __restrict__ x, const float* __restrict__ bias,
                       const int* __restrict__ mask,
                       short* __restrict__ xb, float* __restrict__ biasS,
                       float* __restrict__ maskF)
{
  const int idx = blockIdx.x * 256 + threadIdx.x;
  if (idx < VEC_X) {
    const int j = idx * 4;
    const f32x4 v = *(const f32x4*)&x[j];
    s16x4 st;
#pragma unroll
    for (int r = 0; r < 4; ++r) st[r] = f2bf(v[r]);
    *(s16x4*)&xb[j] = st;
  } else if (idx < VEC_X + VEC_BIAS) {
    const int j = (idx - VEC_X) * 4;
    f32x4 v = *(const f32x4*)&bias[j];
#pragma unroll
    for (int r = 0; r < 4; ++r) v[r] *= 1.4426950408889634f;
    *(f32x4*)&biasS[j] = v;
  } else if (idx < PREP_KTOT) {
    const int j = idx - (VEC_X + VEC_BIAS);
    maskF[j] = mask[j] ? 1.0f : 0.0f;
  }
}

// ---------------------------------------------------------------------------
// prep_w: LDS-tiled 64x64 transposes (coalesced f32x4 reads, bf16x8 writes).
//  blocks 0..127:  Wt1[n][k] (n-tile = bid&31, k-tile = bid>>5); region by n0
//  blocks 128..159: WoT[n][k] from Wo[k][n]
// ---------------------------------------------------------------------------
__global__ void prep_w(const float* __restrict__ Wq, const float* __restrict__ Wkv,
                       const float* __restrict__ Wg, const float* __restrict__ Wo,
                       short* __restrict__ Wt1, short* __restrict__ WoT)
{
  __shared__ short Ls[64][66];                    // +2 pad: bank spread
  const int t = threadIdx.x;
  int bid = blockIdx.x;
  const float* src; int srcStride, n0, k0, dstStride; short* dst;
  if (bid < 128) {
    const int nt = bid & 31, kt = bid >> 5;       // 32 n-tiles x 4 k-tiles
    n0 = nt * 64; k0 = kt * 64;
    dst = Wt1; dstStride = 256;
    if (n0 < 512)       { src = Wq  + n0;          srcStride = 512;  }
    else if (n0 < 1536) { src = Wkv + (n0 - 512);  srcStride = 1024; }
    else                { src = Wg  + (n0 - 1536); srcStride = 512;  }
  } else {
    bid -= 128;
    const int nt = bid & 3, kt = bid >> 2;        // 4 n-tiles x 8 k-tiles
    n0 = nt * 64; k0 = kt * 64;
    dst = WoT; dstStride = 512;
    src = Wo + n0; srcStride = 256;
  }
  {
    const int row0 = t >> 4, c4 = (t & 15) * 4;   // coalesced 256B per 16 lanes
#pragma unroll
    for (int i = 0; i < 4; ++i) {
      const int row = row0 + i * 16;
      const f32x4 v = *(const f32x4*)&src[(size_t)(k0 + row) * srcStride + c4];
      s16x4 st;
#pragma unroll
      for (int r = 0; r < 4; ++r) st[r] = f2bf(v[r]);
      *(s16x4*)&Ls[row][c4] = st;
    }
  }
  __syncthreads();
  {
    const int nr = t >> 2, kc = (t & 3) * 16;     // 4 lanes cover one 128B run
    bf16x8 o0, o1;
#pragma unroll
    for (int j = 0; j < 8; ++j) o0[j] = Ls[kc + j][nr];
#pragma unroll
    for (int j = 0; j < 8; ++j) o1[j] = Ls[kc + 8 + j][nr];
    *(bf16x8*)&dst[(size_t)(n0 + nr) * dstStride + k0 + kc] = o0;
    *(bf16x8*)&dst[(size_t)(n0 + nr) * dstStride + k0 + kc + 8] = o1;
  }
}

// ---------------------------------------------------------------------------
// GEMM1: C = xb[32768,256] @ Wt1^T  (N=2048 fused Q|K|V|G), all bf16.
// BK=64 interval, LDS-staged coalesced epilogue (frozen).
// NEW: chunked-bijective XCD remap -- each XCD owns a contiguous m-range,
// its 16 n-blocks per m run consecutively (X slice L2-hot, Wt1 L2-resident).
// ---------------------------------------------------------------------------
__global__ __launch_bounds__(256, 2) void gemm_qkvg(
    const short* __restrict__ X, const short* __restrict__ Wt,
    const float* __restrict__ bg,
    short* __restrict__ Q, short* __restrict__ Kb,
    short* __restrict__ Vt, short* __restrict__ G)
{
  __shared__ __align__(16) short SM[16384];        // As[2]|Bs[2] staging, reused
  short* As0 = &SM[0];
  short* As1 = &SM[4096];
  short* Bs0 = &SM[8192];
  short* Bs1 = &SM[12288];
  const int tid = threadIdx.x;
  const int w = tid >> 6, lane = tid & 63;
  const int m = lane & 15, q = lane >> 4;
  // XCD-chunked remap (nwg = 4096, bijective)
  const int L = blockIdx.x + (blockIdx.y << 4);
  const int V = (L & 7) * 512 + (L >> 3);
  const int vx = V & 15, vy = V >> 4;
  const int n0 = vx * 128, m0 = vy * 128;
  const int region = vx >> 2;                   // 0=Q 1=K 2=V 3=G
  const bool vreg = (region == 2);
  const int ric = lane >> 2, cslot = lane & 3;
  const int csw = cslot ^ ((ric >> 1) & 3);
  const int wr = (w >> 1) * 64, wc = (w & 1) * 64;
  const int rsw = (m >> 1) & 3;
  f32x4 acc[4][4] = {};
  for (int k0 = 0; k0 < DIM_; k0 += 64) {
    __syncthreads();
#pragma unroll
    for (int s = 0; s < 2; ++s) {
      const int rr = w * 32 + s * 16;
      cp16(X  + (size_t)(m0 + rr + ric) * DIM_ + (k0 + csw * 8),      &As0[rr * 32]);
      cp16(Wt + (size_t)(n0 + rr + ric) * DIM_ + (k0 + csw * 8),      &Bs0[rr * 32]);
      cp16(X  + (size_t)(m0 + rr + ric) * DIM_ + (k0 + 32 + csw * 8), &As1[rr * 32]);
      cp16(Wt + (size_t)(n0 + rr + ric) * DIM_ + (k0 + 32 + csw * 8), &Bs1[rr * 32]);
    }
    __syncthreads();
#pragma unroll
    for (int kh = 0; kh < 2; ++kh) {
      const short* Ap = kh ? As1 : As0;
      const short* Bp = kh ? Bs1 : Bs0;
      bf16x8 af[4], bfv[4];
#pragma unroll
      for (int t = 0; t < 4; ++t) {
        af[t]  = *(const bf16x8*)&Ap[(wr + t * 16 + m) * 32 + ((q ^ rsw) * 8)];
        bfv[t] = *(const bf16x8*)&Bp[(wc + t * 16 + m) * 32 + ((q ^ rsw) * 8)];
      }
      if (vreg) {
#pragma unroll
        for (int ti = 0; ti < 4; ++ti)
#pragma unroll
          for (int tj = 0; tj < 4; ++tj)
            acc[ti][tj] = mfma16(af[ti], bfv[tj], acc[ti][tj]);
      } else {
#pragma unroll
        for (int ti = 0; ti < 4; ++ti)
#pragma unroll
          for (int tj = 0; tj < 4; ++tj)
            acc[ti][tj] = mfma16(bfv[tj], af[ti], acc[ti][tj]);  // transposed C
      }
    }
  }

  // ---- LDS-staged coalesced epilogue ----
  __syncthreads();
  short* Ls = SM;                                  // 128x128 shorts
  const int nb = n0 & 511;
  if (vreg) {
#pragma unroll
    for (int ti = 0; ti < 4; ++ti) {
      const int sl = (wr + ti * 16) / 4 + q;
#pragma unroll
      for (int tj = 0; tj < 4; ++tj) {
        const int cl = wc + tj * 16 + m;
        s16x4 st;
#pragma unroll
        for (int r = 0; r < 4; ++r) st[r] = f2bf(acc[ti][tj][r]);
        *(s16x4*)&Ls[cl * 128 + ((sl ^ ((cl & 15) << 1)) << 2)] = st;
      }
    }
  } else {
#pragma unroll
    for (int ti = 0; ti < 4; ++ti) {
      const int rl = wr + ti * 16 + m;
#pragma unroll
      for (int tj = 0; tj < 4; ++tj) {
        const int cl = wc + tj * 16 + q * 4;
        f32x4 v = acc[ti][tj];
        if (region == 3) {
          const f32x4 bg4 = *(const f32x4*)&bg[nb + cl];
#pragma unroll
          for (int r = 0; r < 4; ++r) v[r] += bg4[r];
        }
        s16x4 st;
#pragma unroll
        for (int r = 0; r < 4; ++r) st[r] = f2bf(v[r]);
        *(s16x4*)&Ls[rl * 128 + (((cl >> 2) ^ ((rl & 15) << 1)) << 2)] = st;
      }
    }
  }
  __syncthreads();
  const int bblk = m0 >> 9, nbase = m0 & 511;
#pragma unroll
  for (int k = 0; k < 8; ++k) {
    const int ch = k * 256 + tid;
    const int rr = ch >> 4, off = ch & 15;
    const bf16x8 vv =
        *(const bf16x8*)&Ls[rr * 128 + ((((off << 1) ^ ((rr & 15) << 1))) << 2)];
    if (vreg) {
      const int cg = nb + rr;
      const int h = cg >> 6, d = cg & 63;
      *(bf16x8*)&Vt[((size_t)(bblk * 8 + h) * 64 + d) * 512 + nbase + off * 8] = vv;
    } else if (region == 3) {
      *(bf16x8*)&G[(size_t)(m0 + rr) * 512 + nb + off * 8] = vv;
    } else {
      const int cg = nb + off * 8;
      const int h = cg >> 6, d0 = cg & 63;
      short* dst = (region == 0) ? Q : Kb;
      *(bf16x8*)&dst[((size_t)(bblk * 8 + h) * 512 + nbase + rr) * 64 + d0] = vv;
    }
  }
}

// ---------------------------------------------------------------------------
// Attention (FROZEN at R7 state: KVBLK=32, 20KB LDS, l via MFMA-ones,
// vsw swizzle, setprio, (h,iq,b) grid). ~103 us, structural plateau.
// ---------------------------------------------------------------------------
__global__ __launch_bounds__(256, 4) void attn_k(
    const short* __restrict__ Q, const short* __restrict__ K,
    const short* __restrict__ Vt, const float* __restrict__ biasS,
    const float* __restrict__ maskF, short* __restrict__ G)
{
  __shared__ __align__(16) short Ks[2][32 * 64];   // [j][d], xor-swizzled by j&7
  __shared__ __align__(16) short Vs[2][64 * 32];   // [d][j], slot-xor (d^d>>2)&3
  __shared__ __align__(16) short Pall[4][16 * 32]; // per-wave, slot-xor (i^i>>2)&3
  const int tid = threadIdx.x;
  const int w = tid >> 6, lane = tid & 63;
  const int m = lane & 15, q = lane >> 4;
  const int m7 = m & 7;
  const int vsw = (m ^ (m >> 2)) & 3;              // bank-spread swizzle, 64B rows
  const int h = blockIdx.x, iq = blockIdx.y, b = blockIdx.z;
  const int i0w = iq * 128 + w * 32;               // this wave's first Q row
  const size_t bh = (size_t)b * 8 + h;
  const short* Qp = Q + (bh * 512 + i0w) * 64;
  const short* Kp = K + bh * 512 * 64;
  const short* Vp = Vt + bh * 64 * 512;
  const float* mkp = maskF + b * 512;
  short* Ps = Pall[w];

  const int srow = lane >> 3;                      // 0..7
  const int gchunk = (lane & 7) ^ srow;            // global d-chunk (xor by row&7)
  const int vrow = lane >> 2;                      // 0..15
  const int gchunkV = (lane & 3) ^ ((vrow ^ (vrow >> 2)) & 3);

  bf16x8 vones;
#pragma unroll
  for (int r = 0; r < 8; ++r) vones[r] = (short)0x3F80;

  bf16x8 qf[2][2];
#pragma unroll
  for (int it = 0; it < 2; ++it) {
    qf[it][0] = *(const bf16x8*)&Qp[(it * 16 + m) * 64 + q * 8];
    qf[it][1] = *(const bf16x8*)&Qp[(it * 16 + m) * 64 + 32 + q * 8];
  }
  float miF[2];
#pragma unroll
  for (int it = 0; it < 2; ++it) miF[it] = mkp[i0w + it * 16 + m];

  cp16(Kp + (size_t)(w * 8 + srow) * 64 + gchunk * 8, &Ks[0][w * 8 * 64]);
  cp16(Vp + (size_t)(w * 16 + vrow) * 512 + gchunkV * 8, &Vs[0][w * 16 * 32]);

  f32x4 o[2][4] = {};
  f32x4 lacc[2] = {};                              // l in o-layout (row = q*4+r)
  __syncthreads();                                 // chunk 0 staged

  const float SCL = 0.125f * 1.4426950408889634f;  // scale * log2(e)
  for (int c = 0; c < 16; ++c) {
    const int p = c & 1;
    if (c < 15) {                                  // prefetch next chunk
      const int jn = (c + 1) * 32;
      cp16(Kp + (size_t)(jn + w * 8 + srow) * 64 + gchunk * 8, &Ks[p ^ 1][w * 8 * 64]);
      cp16(Vp + (size_t)(w * 16 + vrow) * 512 + jn + gchunkV * 8, &Vs[p ^ 1][w * 16 * 32]);
    }
    f32x4 mjf[2];
#pragma unroll
    for (int jt = 0; jt < 2; ++jt)
      mjf[jt] = *(const f32x4*)&mkp[c * 32 + jt * 16 + q * 4];

    f32x4 s[2][2];
    __builtin_amdgcn_s_setprio(1);
#pragma unroll
    for (int jt = 0; jt < 2; ++jt) {
      const bf16x8 ka = *(const bf16x8*)&Ks[p][(jt * 16 + m) * 64 + ((q ^ m7) * 8)];
      const bf16x8 kb = *(const bf16x8*)&Ks[p][(jt * 16 + m) * 64 + (((4 + q) ^ m7) * 8)];
#pragma unroll
      for (int it = 0; it < 2; ++it) {
        f32x4 a = {};
        a = mfma16(ka, qf[it][0], a);
        s[it][jt] = mfma16(kb, qf[it][1], a);
      }
    }
    __builtin_amdgcn_s_setprio(0);
#pragma unroll
    for (int it = 0; it < 2; ++it) {
      const float* bp = biasS + ((size_t)h * 512 + i0w + it * 16 + m) * 512 + c * 32;
      f32x4 bv[2];
#pragma unroll
      for (int jt = 0; jt < 2; ++jt)
        bv[jt] = *(const f32x4*)&bp[jt * 16 + q * 4];
#pragma unroll
      for (int jt = 0; jt < 2; ++jt) {
        s16x4 st;
#pragma unroll
        for (int r = 0; r < 4; ++r) {
          const float v = fmaf(s[it][jt][r], SCL, bv[jt][r]);
          float e = exp2f(v) * mjf[jt][r];
          e = (miF[it] != 0.0f) ? e : 1.0f;        // fully-masked row -> uniform
          st[r] = (short)(__float_as_uint(e) >> 16);  // trunc pack
        }
        *(s16x4*)&Ps[m * 32 + (((jt * 2 + (q >> 1)) ^ vsw) * 8) + (q & 1) * 4] = st;
      }
      const bf16x8 pa = *(const bf16x8*)&Ps[m * 32 + ((q ^ vsw) * 8)];
      __builtin_amdgcn_s_setprio(1);
      lacc[it] = mfma16(pa, vones, lacc[it]);
#pragma unroll
      for (int dt = 0; dt < 4; ++dt) {
        const bf16x8 va = *(const bf16x8*)&Vs[p][(dt * 16 + m) * 32 + ((q ^ vsw) * 8)];
        o[it][dt] = mfma16(pa, va, o[it][dt]);
      }
      __builtin_amdgcn_s_setprio(0);
    }
    __syncthreads();  // Ks/Vs[p] reads done; prefetch (p^1) drained
  }

  const int colb = h * 64;
#pragma unroll
  for (int it = 0; it < 2; ++it) {
    f32x4 lr;
#pragma unroll
    for (int r = 0; r < 4; ++r) lr[r] = 1.0f / lacc[it][r];
#pragma unroll
    for (int dt = 0; dt < 4; ++dt)
#pragma unroll
      for (int r = 0; r < 4; ++r) {
        const int row = i0w + it * 16 + q * 4 + r;
        const size_t addr = ((size_t)b * 512 + row) * 512 + colb + dt * 16 + m;
        const float gate = bf2f(G[addr]);
        G[addr] = f2bf(o[it][dt][r] * lr[r] * gate);
      }
  }
}

// ---------------------------------------------------------------------------
// GEMM3: out = OG[32768,512] @ Wo + bo.  BK=64 interval, 64x128 tiles.
// NEW: chunked-bijective XCD remap (nwg = 1024).
// ---------------------------------------------------------------------------
__global__ __launch_bounds__(256, 2) void gemm_og(
    const short* __restrict__ A, const short* __restrict__ Bt,
    const float* __restrict__ bo, float* __restrict__ out)
{
  __shared__ __align__(16) short As[2][64 * 32];
  __shared__ __align__(16) short Bs[2][128 * 32];
  const int tid = threadIdx.x;
  const int w = tid >> 6, lane = tid & 63;
  const int m = lane & 15, q = lane >> 4;
  const int L = blockIdx.x + (blockIdx.y << 1);
  const int V = (L & 7) * 128 + (L >> 3);
  const int n0 = (V & 1) * 128, m0 = (V >> 1) * 64;
  const int ric = lane >> 2, cslot = lane & 3;
  const int csw = cslot ^ ((ric >> 1) & 3);
  const int wr = (w >> 1) * 32, wc = (w & 1) * 64;
  const int rsw = (m >> 1) & 3;
  f32x4 acc[2][4] = {};
  for (int k0 = 0; k0 < INNER_; k0 += 64) {
    __syncthreads();
#pragma unroll
    for (int kh = 0; kh < 2; ++kh) {
      const int kk = k0 + kh * 32;
      cp16(A + (size_t)(m0 + w * 16 + ric) * INNER_ + (kk + csw * 8), &As[kh][w * 16 * 32]);
#pragma unroll
      for (int s = 0; s < 2; ++s) {
        const int rr = w * 32 + s * 16;
        cp16(Bt + (size_t)(n0 + rr + ric) * INNER_ + (kk + csw * 8), &Bs[kh][rr * 32]);
      }
    }
    __syncthreads();
#pragma unroll
    for (int kh = 0; kh < 2; ++kh) {
      bf16x8 af[2], bfv[4];
#pragma unroll
      for (int t = 0; t < 2; ++t)
        af[t]  = *(const bf16x8*)&As[kh][(wr + t * 16 + m) * 32 + ((q ^ rsw) * 8)];
#pragma unroll
      for (int t = 0; t < 4; ++t)
        bfv[t] = *(const bf16x8*)&Bs[kh][(wc + t * 16 + m) * 32 + ((q ^ rsw) * 8)];
#pragma unroll
      for (int ti = 0; ti < 2; ++ti)
#pragma unroll
        for (int tj = 0; tj < 4; ++tj)
          acc[ti][tj] = mfma16(bfv[tj], af[ti], acc[ti][tj]);   // transposed C
    }
  }
#pragma unroll
  for (int ti = 0; ti < 2; ++ti) {
    const int row = m0 + wr + ti * 16 + m;       // one output row per lane
#pragma unroll
    for (int tj = 0; tj < 4; ++tj) {
      const int c0 = n0 + wc + tj * 16 + q * 4;  // 4 consecutive out-columns
      const f32x4 bo4 = *(const f32x4*)&bo[c0];
      f32x4 v;
#pragma unroll
      for (int r = 0; r < 4; ++r) v[r] = acc[ti][tj][r] + bo4[r];
      *(f32x4*)&out[(size_t)row * 256 + c0] = v;
    }
  }
}

// ---------------------------------------------------------------------------
extern "C" void kernel_launch(void* const* d_in, const int* in_sizes, int n_in,
                              void* d_out, int out_size, void* d_ws, size_t ws_size,
                              hipStream_t stream)
{
  (void)in_sizes; (void)n_in; (void)out_size; (void)ws_size;
  const float* x    = (const float*)d_in[0];
  const int*   mask = (const int*)d_in[1];
  const float* bias = (const float*)d_in[2];
  const float* Wq   = (const float*)d_in[3];
  const float* Wkv  = (const float*)d_in[4];
  const float* Wo   = (const float*)d_in[5];
  const float* bo   = (const float*)d_in[6];
  const float* Wg   = (const float*)d_in[7];
  const float* bg   = (const float*)d_in[8];
  float* out = (float*)d_out;

  char* ws = (char*)d_ws;
  size_t off = 0;
  short* Wt1   = (short*)(ws + off); off += (size_t)2048 * 256 * 2;         // 1.0 MiB
  short* WoT   = (short*)(ws + off); off += (size_t)256 * 512 * 2;          // 0.25 MiB
  short* xb    = (short*)(ws + off); off += (size_t)32768 * 256 * 2;        // 16 MiB
  short* Qb    = (short*)(ws + off); off += (size_t)B_ * H_ * N_ * DH_ * 2; // 32 MiB
  short* Kb    = (short*)(ws + off); off += (size_t)B_ * H_ * N_ * DH_ * 2; // 32 MiB
  short* Vt    = (short*)(ws + off); off += (size_t)B_ * H_ * DH_ * N_ * 2; // 32 MiB
  short* G     = (short*)(ws + off); off += (size_t)B_ * N_ * INNER_ * 2;   // 32 MiB
  float* biasS = (float*)(ws + off); off += (size_t)H_ * N_ * N_ * 4;       // 8 MiB
  float* maskF = (float*)(ws + off); off += (size_t)B_ * N_ * 4;            // 128 KiB

  prep_k<<<PREP_KTOT / 256, 256, 0, stream>>>(x, bias, mask, xb, biasS, maskF);
  prep_w<<<160, 256, 0, stream>>>(Wq, Wkv, Wg, Wo, Wt1, WoT);
  gemm_qkvg<<<dim3(16, 256), 256, 0, stream>>>(xb, Wt1, bg, Qb, Kb, Vt, G);
  attn_k<<<dim3(8, 4, 64), 256, 0, stream>>>(Qb, Kb, Vt, biasS, maskF, G);
  gemm_og<<<dim3(2, 512), 256, 0, stream>>>(G, WoT, bo, out);
}

// Round 12
// 264.965 us; speedup vs baseline: 1.1675x; 1.0085x over previous
//
#include <hip/hip_runtime.h>
#include <stdint.h>

// Problem constants
#define B_    64
#define N_    512
#define DIM_  256
#define H_    8
#define DH_   64
#define INNER_ 512

typedef __attribute__((ext_vector_type(8))) short bf16x8;
typedef __attribute__((ext_vector_type(4))) float f32x4;
typedef __attribute__((ext_vector_type(4))) short s16x4;

typedef const __attribute__((address_space(1))) void* gas_ptr;
typedef __attribute__((address_space(3))) void* las_ptr;

__device__ __forceinline__ short f2bf(float f) {
  unsigned int u = __float_as_uint(f);
  u += 0x7fffu + ((u >> 16) & 1u);          // RNE
  return (short)(u >> 16);
}
__device__ __forceinline__ float bf2f(short s) {
  return __uint_as_float(((unsigned int)(unsigned short)s) << 16);
}
__device__ __forceinline__ void cp16(const void* g, void* l) {
  __builtin_amdgcn_global_load_lds((gas_ptr)g, (las_ptr)l, 16, 0, 0);
}
__device__ __forceinline__ f32x4 mfma16(bf16x8 a, bf16x8 b, f32x4 c) {
  return __builtin_amdgcn_mfma_f32_16x16x32_bf16(a, b, c, 0, 0, 0);
}

// ---------------------------------------------------------------------------
// prep_all: elementwise conversions (blocks 0..10367) + LDS-tiled weight
// transposes (blocks 10368..10527). Merged to save one launch.
// ---------------------------------------------------------------------------
#define PREP_X    (32768 * 256)
#define PREP_BIAS (8 * 512 * 512)
#define PREP_MASK (64 * 512)
#define VEC_X     (PREP_X / 4)
#define VEC_BIAS  (PREP_BIAS / 4)
#define PREP_KTOT (VEC_X + VEC_BIAS + PREP_MASK)   // 2,654,208 = 10368*256
#define PREP_KBLK (PREP_KTOT / 256)                // 10368

__global__ void prep_all(const float* __restrict__ x, const float* __restrict__ bias,
                         const int* __restrict__ mask,
                         const float* __restrict__ Wq, const float* __restrict__ Wkv,
                         const float* __restrict__ Wg, const float* __restrict__ Wo,
                         short* __restrict__ xb, float* __restrict__ biasS,
                         float* __restrict__ maskF,
                         short* __restrict__ Wt1, short* __restrict__ WoT)
{
  __shared__ short Ls[64][66];                    // +2 pad (transpose blocks only)
  const int t = threadIdx.x;
  if (blockIdx.x < PREP_KBLK) {
    const int idx = blockIdx.x * 256 + t;
    if (idx < VEC_X) {
      const int j = idx * 4;
      const f32x4 v = *(const f32x4*)&x[j];
      s16x4 st;
#pragma unroll
      for (int r = 0; r < 4; ++r) st[r] = f2bf(v[r]);
      *(s16x4*)&xb[j] = st;
    } else if (idx < VEC_X + VEC_BIAS) {
      const int j = (idx - VEC_X) * 4;
      f32x4 v = *(const f32x4*)&bias[j];
#pragma unroll
      for (int r = 0; r < 4; ++r) v[r] *= 1.4426950408889634f;
      *(f32x4*)&biasS[j] = v;
    } else if (idx < PREP_KTOT) {
      const int j = idx - (VEC_X + VEC_BIAS);
      maskF[j] = mask[j] ? 1.0f : 0.0f;
    }
    return;
  }
  int bid = blockIdx.x - PREP_KBLK;
  const float* src; int srcStride, n0, k0, dstStride; short* dst;
  if (bid < 128) {
    const int nt = bid & 31, kt = bid >> 5;       // 32 n-tiles x 4 k-tiles
    n0 = nt * 64; k0 = kt * 64;
    dst = Wt1; dstStride = 256;
    if (n0 < 512)       { src = Wq  + n0;          srcStride = 512;  }
    else if (n0 < 1536) { src = Wkv + (n0 - 512);  srcStride = 1024; }
    else                { src = Wg  + (n0 - 1536); srcStride = 512;  }
  } else {
    bid -= 128;
    const int nt = bid & 3, kt = bid >> 2;        // 4 n-tiles x 8 k-tiles
    n0 = nt * 64; k0 = kt * 64;
    dst = WoT; dstStride = 512;
    src = Wo + n0; srcStride = 256;
  }
  {
    const int row0 = t >> 4, c4 = (t & 15) * 4;   // coalesced 256B per 16 lanes
#pragma unroll
    for (int i = 0; i < 4; ++i) {
      const int row = row0 + i * 16;
      const f32x4 v = *(const f32x4*)&src[(size_t)(k0 + row) * srcStride + c4];
      s16x4 st;
#pragma unroll
      for (int r = 0; r < 4; ++r) st[r] = f2bf(v[r]);
      *(s16x4*)&Ls[row][c4] = st;
    }
  }
  __syncthreads();
  {
    const int nr = t >> 2, kc = (t & 3) * 16;     // 4 lanes cover one 128B run
    bf16x8 o0, o1;
#pragma unroll
    for (int j = 0; j < 8; ++j) o0[j] = Ls[kc + j][nr];
#pragma unroll
    for (int j = 0; j < 8; ++j) o1[j] = Ls[kc + 8 + j][nr];
    *(bf16x8*)&dst[(size_t)(n0 + nr) * dstStride + k0 + kc] = o0;
    *(bf16x8*)&dst[(size_t)(n0 + nr) * dstStride + k0 + kc + 8] = o1;
  }
}

// ---------------------------------------------------------------------------
// GEMM1 (frozen): BK=64 interval, LDS-staged coalesced epilogue, XCD remap.
// ---------------------------------------------------------------------------
__global__ __launch_bounds__(256, 2) void gemm_qkvg(
    const short* __restrict__ X, const short* __restrict__ Wt,
    const float* __restrict__ bg,
    short* __restrict__ Q, short* __restrict__ Kb,
    short* __restrict__ Vt, short* __restrict__ G)
{
  __shared__ __align__(16) short SM[16384];        // As[2]|Bs[2] staging, reused
  short* As0 = &SM[0];
  short* As1 = &SM[4096];
  short* Bs0 = &SM[8192];
  short* Bs1 = &SM[12288];
  const int tid = threadIdx.x;
  const int w = tid >> 6, lane = tid & 63;
  const int m = lane & 15, q = lane >> 4;
  const int L = blockIdx.x + (blockIdx.y << 4);
  const int V = (L & 7) * 512 + (L >> 3);
  const int vx = V & 15, vy = V >> 4;
  const int n0 = vx * 128, m0 = vy * 128;
  const int region = vx >> 2;                   // 0=Q 1=K 2=V 3=G
  const bool vreg = (region == 2);
  const int ric = lane >> 2, cslot = lane & 3;
  const int csw = cslot ^ ((ric >> 1) & 3);
  const int wr = (w >> 1) * 64, wc = (w & 1) * 64;
  const int rsw = (m >> 1) & 3;
  f32x4 acc[4][4] = {};
  for (int k0 = 0; k0 < DIM_; k0 += 64) {
    __syncthreads();
#pragma unroll
    for (int s = 0; s < 2; ++s) {
      const int rr = w * 32 + s * 16;
      cp16(X  + (size_t)(m0 + rr + ric) * DIM_ + (k0 + csw * 8),      &As0[rr * 32]);
      cp16(Wt + (size_t)(n0 + rr + ric) * DIM_ + (k0 + csw * 8),      &Bs0[rr * 32]);
      cp16(X  + (size_t)(m0 + rr + ric) * DIM_ + (k0 + 32 + csw * 8), &As1[rr * 32]);
      cp16(Wt + (size_t)(n0 + rr + ric) * DIM_ + (k0 + 32 + csw * 8), &Bs1[rr * 32]);
    }
    __syncthreads();
#pragma unroll
    for (int kh = 0; kh < 2; ++kh) {
      const short* Ap = kh ? As1 : As0;
      const short* Bp = kh ? Bs1 : Bs0;
      bf16x8 af[4], bfv[4];
#pragma unroll
      for (int t = 0; t < 4; ++t) {
        af[t]  = *(const bf16x8*)&Ap[(wr + t * 16 + m) * 32 + ((q ^ rsw) * 8)];
        bfv[t] = *(const bf16x8*)&Bp[(wc + t * 16 + m) * 32 + ((q ^ rsw) * 8)];
      }
      if (vreg) {
#pragma unroll
        for (int ti = 0; ti < 4; ++ti)
#pragma unroll
          for (int tj = 0; tj < 4; ++tj)
            acc[ti][tj] = mfma16(af[ti], bfv[tj], acc[ti][tj]);
      } else {
#pragma unroll
        for (int ti = 0; ti < 4; ++ti)
#pragma unroll
          for (int tj = 0; tj < 4; ++tj)
            acc[ti][tj] = mfma16(bfv[tj], af[ti], acc[ti][tj]);  // transposed C
      }
    }
  }

  // ---- LDS-staged coalesced epilogue ----
  __syncthreads();
  short* Ls = SM;                                  // 128x128 shorts
  const int nb = n0 & 511;
  if (vreg) {
#pragma unroll
    for (int ti = 0; ti < 4; ++ti) {
      const int sl = (wr + ti * 16) / 4 + q;
#pragma unroll
      for (int tj = 0; tj < 4; ++tj) {
        const int cl = wc + tj * 16 + m;
        s16x4 st;
#pragma unroll
        for (int r = 0; r < 4; ++r) st[r] = f2bf(acc[ti][tj][r]);
        *(s16x4*)&Ls[cl * 128 + ((sl ^ ((cl & 15) << 1)) << 2)] = st;
      }
    }
  } else {
#pragma unroll
    for (int ti = 0; ti < 4; ++ti) {
      const int rl = wr + ti * 16 + m;
#pragma unroll
      for (int tj = 0; tj < 4; ++tj) {
        const int cl = wc + tj * 16 + q * 4;
        f32x4 v = acc[ti][tj];
        if (region == 3) {
          const f32x4 bg4 = *(const f32x4*)&bg[nb + cl];
#pragma unroll
          for (int r = 0; r < 4; ++r) v[r] += bg4[r];
        }
        s16x4 st;
#pragma unroll
        for (int r = 0; r < 4; ++r) st[r] = f2bf(v[r]);
        *(s16x4*)&Ls[rl * 128 + (((cl >> 2) ^ ((rl & 15) << 1)) << 2)] = st;
      }
    }
  }
  __syncthreads();
  const int bblk = m0 >> 9, nbase = m0 & 511;
#pragma unroll
  for (int k = 0; k < 8; ++k) {
    const int ch = k * 256 + tid;
    const int rr = ch >> 4, off = ch & 15;
    const bf16x8 vv =
        *(const bf16x8*)&Ls[rr * 128 + ((((off << 1) ^ ((rr & 15) << 1))) << 2)];
    if (vreg) {
      const int cg = nb + rr;
      const int h = cg >> 6, d = cg & 63;
      *(bf16x8*)&Vt[((size_t)(bblk * 8 + h) * 64 + d) * 512 + nbase + off * 8] = vv;
    } else if (region == 3) {
      *(bf16x8*)&G[(size_t)(m0 + rr) * 512 + nb + off * 8] = vv;
    } else {
      const int cg = nb + off * 8;
      const int h = cg >> 6, d0 = cg & 63;
      short* dst = (region == 0) ? Q : Kb;
      *(bf16x8*)&dst[((size_t)(bblk * 8 + h) * 512 + nbase + rr) * 64 + d0] = vv;
    }
  }
}

// ---------------------------------------------------------------------------
// Attention. NEW (vmcnt-FIFO fix, mechanism from R6-null analysis):
//  - mask staged to LDS ONCE (2KB): per-chunk mask reads become LDS
//    broadcasts, off the global-load FIFO entirely.
//  - bias loads hoisted to chunk-top BEFORE the cp16 prefetch: the compiler
//    can then wait for bias with vmcnt(2) while the K/V prefetch stays in
//    flight until the barrier (FIFO: waiting for OLDER ops doesn't drain
//    younger cp16s). Only 16 extra live VGPRs (vs R2's 48 which spilled).
// Watch: WRITE_SIZE must stay ~32.8MB (no spill); VGPR ~80-96 expected.
// ---------------------------------------------------------------------------
__global__ __launch_bounds__(256, 4) void attn_k(
    const short* __restrict__ Q, const short* __restrict__ K,
    const short* __restrict__ Vt, const float* __restrict__ biasS,
    const float* __restrict__ maskF, short* __restrict__ G)
{
  __shared__ __align__(16) short Ks[2][32 * 64];   // [j][d], xor-swizzled by j&7
  __shared__ __align__(16) short Vs[2][64 * 32];   // [d][j], slot-xor (d^d>>2)&3
  __shared__ __align__(16) short Pall[4][16 * 32]; // per-wave, slot-xor (i^i>>2)&3
  __shared__ __align__(16) float Ms[512];          // mask row (staged once)
  const int tid = threadIdx.x;
  const int w = tid >> 6, lane = tid & 63;
  const int m = lane & 15, q = lane >> 4;
  const int m7 = m & 7;
  const int vsw = (m ^ (m >> 2)) & 3;              // bank-spread swizzle, 64B rows
  const int h = blockIdx.x, iq = blockIdx.y, b = blockIdx.z;
  const int i0w = iq * 128 + w * 32;               // this wave's first Q row
  const size_t bh = (size_t)b * 8 + h;
  const short* Qp = Q + (bh * 512 + i0w) * 64;
  const short* Kp = K + bh * 512 * 64;
  const short* Vp = Vt + bh * 64 * 512;
  const float* mkp = maskF + b * 512;
  short* Ps = Pall[w];

  const int srow = lane >> 3;                      // 0..7
  const int gchunk = (lane & 7) ^ srow;            // global d-chunk (xor by row&7)
  const int vrow = lane >> 2;                      // 0..15
  const int gchunkV = (lane & 3) ^ ((vrow ^ (vrow >> 2)) & 3);

  bf16x8 vones;
#pragma unroll
  for (int r = 0; r < 8; ++r) vones[r] = (short)0x3F80;

  bf16x8 qf[2][2];
#pragma unroll
  for (int it = 0; it < 2; ++it) {
    qf[it][0] = *(const bf16x8*)&Qp[(it * 16 + m) * 64 + q * 8];
    qf[it][1] = *(const bf16x8*)&Qp[(it * 16 + m) * 64 + 32 + q * 8];
  }
  float miF[2];
#pragma unroll
  for (int it = 0; it < 2; ++it) miF[it] = mkp[i0w + it * 16 + m];

  // stage chunk 0 K/V + the whole mask row (waves 0-1)
  cp16(Kp + (size_t)(w * 8 + srow) * 64 + gchunk * 8, &Ks[0][w * 8 * 64]);
  cp16(Vp + (size_t)(w * 16 + vrow) * 512 + gchunkV * 8, &Vs[0][w * 16 * 32]);
  if (w < 2) cp16(mkp + (w * 64 + lane) * 4, &Ms[w * 256]);

  f32x4 o[2][4] = {};
  f32x4 lacc[2] = {};                              // l in o-layout (row = q*4+r)
  __syncthreads();                                 // chunk 0 + mask staged

  const float SCL = 0.125f * 1.4426950408889634f;  // scale * log2(e)
  const float* bpc0 = biasS + ((size_t)h * 512 + i0w) * 512;
  for (int c = 0; c < 16; ++c) {
    const int p = c & 1;

    // 1) bias loads FIRST (oldest in FIFO -> waiting for them leaves the
    //    younger cp16 prefetch in flight)
    f32x4 bvv[2][2];
#pragma unroll
    for (int it = 0; it < 2; ++it)
#pragma unroll
      for (int jt = 0; jt < 2; ++jt)
        bvv[it][jt] = *(const f32x4*)&bpc0[(it * 16 + m) * 512 + c * 32 + jt * 16 + q * 4];

    // 2) prefetch next chunk
    if (c < 15) {
      const int jn = (c + 1) * 32;
      cp16(Kp + (size_t)(jn + w * 8 + srow) * 64 + gchunk * 8, &Ks[p ^ 1][w * 8 * 64]);
      cp16(Vp + (size_t)(w * 16 + vrow) * 512 + jn + gchunkV * 8, &Vs[p ^ 1][w * 16 * 32]);
    }

    // 3) mask from LDS (broadcast across m-lanes, conflict-free)
    f32x4 mjf[2];
#pragma unroll
    for (int jt = 0; jt < 2; ++jt)
      mjf[jt] = *(const f32x4*)&Ms[c * 32 + jt * 16 + q * 4];

    // 4) QK^T
    f32x4 s[2][2];
    __builtin_amdgcn_s_setprio(1);
#pragma unroll
    for (int jt = 0; jt < 2; ++jt) {
      const bf16x8 ka = *(const bf16x8*)&Ks[p][(jt * 16 + m) * 64 + ((q ^ m7) * 8)];
      const bf16x8 kb = *(const bf16x8*)&Ks[p][(jt * 16 + m) * 64 + (((4 + q) ^ m7) * 8)];
#pragma unroll
      for (int it = 0; it < 2; ++it) {
        f32x4 a = {};
        a = mfma16(ka, qf[it][0], a);
        s[it][jt] = mfma16(kb, qf[it][1], a);
      }
    }
    __builtin_amdgcn_s_setprio(0);

    // 5) softmax + PV
#pragma unroll
    for (int it = 0; it < 2; ++it) {
#pragma unroll
      for (int jt = 0; jt < 2; ++jt) {
        s16x4 st;
#pragma unroll
        for (int r = 0; r < 4; ++r) {
          const float v = fmaf(s[it][jt][r], SCL, bvv[it][jt][r]);
          float e = exp2f(v) * mjf[jt][r];
          e = (miF[it] != 0.0f) ? e : 1.0f;        // fully-masked row -> uniform
          st[r] = (short)(__float_as_uint(e) >> 16);  // trunc pack
        }
        *(s16x4*)&Ps[m * 32 + (((jt * 2 + (q >> 1)) ^ vsw) * 8) + (q & 1) * 4] = st;
      }
      const bf16x8 pa = *(const bf16x8*)&Ps[m * 32 + ((q ^ vsw) * 8)];
      __builtin_amdgcn_s_setprio(1);
      lacc[it] = mfma16(pa, vones, lacc[it]);
#pragma unroll
      for (int dt = 0; dt < 4; ++dt) {
        const bf16x8 va = *(const bf16x8*)&Vs[p][(dt * 16 + m) * 32 + ((q ^ vsw) * 8)];
        o[it][dt] = mfma16(pa, va, o[it][dt]);
      }
      __builtin_amdgcn_s_setprio(0);
    }
    __syncthreads();  // Ks/Vs[p] reads done; prefetch (p^1) drained
  }

  const int colb = h * 64;
#pragma unroll
  for (int it = 0; it < 2; ++it) {
    f32x4 lr;
#pragma unroll
    for (int r = 0; r < 4; ++r) lr[r] = 1.0f / lacc[it][r];
#pragma unroll
    for (int dt = 0; dt < 4; ++dt)
#pragma unroll
      for (int r = 0; r < 4; ++r) {
        const int row = i0w + it * 16 + q * 4 + r;
        const size_t addr = ((size_t)b * 512 + row) * 512 + colb + dt * 16 + m;
        const float gate = bf2f(G[addr]);
        G[addr] = f2bf(o[it][dt][r] * lr[r] * gate);
      }
  }
}

// ---------------------------------------------------------------------------
// GEMM3 (frozen): BK=64 interval, 64x128 tiles, XCD remap.
// ---------------------------------------------------------------------------
__global__ __launch_bounds__(256, 2) void gemm_og(
    const short* __restrict__ A, const short* __restrict__ Bt,
    const float* __restrict__ bo, float* __restrict__ out)
{
  __shared__ __align__(16) short As[2][64 * 32];
  __shared__ __align__(16) short Bs[2][128 * 32];
  const int tid = threadIdx.x;
  const int w = tid >> 6, lane = tid & 63;
  const int m = lane & 15, q = lane >> 4;
  const int L = blockIdx.x + (blockIdx.y << 1);
  const int V = (L & 7) * 128 + (L >> 3);
  const int n0 = (V & 1) * 128, m0 = (V >> 1) * 64;
  const int ric = lane >> 2, cslot = lane & 3;
  const int csw = cslot ^ ((ric >> 1) & 3);
  const int wr = (w >> 1) * 32, wc = (w & 1) * 64;
  const int rsw = (m >> 1) & 3;
  f32x4 acc[2][4] = {};
  for (int k0 = 0; k0 < INNER_; k0 += 64) {
    __syncthreads();
#pragma unroll
    for (int kh = 0; kh < 2; ++kh) {
      const int kk = k0 + kh * 32;
      cp16(A + (size_t)(m0 + w * 16 + ric) * INNER_ + (kk + csw * 8), &As[kh][w * 16 * 32]);
#pragma unroll
      for (int s = 0; s < 2; ++s) {
        const int rr = w * 32 + s * 16;
        cp16(Bt + (size_t)(n0 + rr + ric) * INNER_ + (kk + csw * 8), &Bs[kh][rr * 32]);
      }
    }
    __syncthreads();
#pragma unroll
    for (int kh = 0; kh < 2; ++kh) {
      bf16x8 af[2], bfv[4];
#pragma unroll
      for (int t = 0; t < 2; ++t)
        af[t]  = *(const bf16x8*)&As[kh][(wr + t * 16 + m) * 32 + ((q ^ rsw) * 8)];
#pragma unroll
      for (int t = 0; t < 4; ++t)
        bfv[t] = *(const bf16x8*)&Bs[kh][(wc + t * 16 + m) * 32 + ((q ^ rsw) * 8)];
#pragma unroll
      for (int ti = 0; ti < 2; ++ti)
#pragma unroll
        for (int tj = 0; tj < 4; ++tj)
          acc[ti][tj] = mfma16(bfv[tj], af[ti], acc[ti][tj]);   // transposed C
    }
  }
#pragma unroll
  for (int ti = 0; ti < 2; ++ti) {
    const int row = m0 + wr + ti * 16 + m;       // one output row per lane
#pragma unroll
    for (int tj = 0; tj < 4; ++tj) {
      const int c0 = n0 + wc + tj * 16 + q * 4;  // 4 consecutive out-columns
      const f32x4 bo4 = *(const f32x4*)&bo[c0];
      f32x4 v;
#pragma unroll
      for (int r = 0; r < 4; ++r) v[r] = acc[ti][tj][r] + bo4[r];
      *(f32x4*)&out[(size_t)row * 256 + c0] = v;
    }
  }
}

// ---------------------------------------------------------------------------
extern "C" void kernel_launch(void* const* d_in, const int* in_sizes, int n_in,
                              void* d_out, int out_size, void* d_ws, size_t ws_size,
                              hipStream_t stream)
{
  (void)in_sizes; (void)n_in; (void)out_size; (void)ws_size;
  const float* x    = (const float*)d_in[0];
  const int*   mask = (const int*)d_in[1];
  const float* bias = (const float*)d_in[2];
  const float* Wq   = (const float*)d_in[3];
  const float* Wkv  = (const float*)d_in[4];
  const float* Wo   = (const float*)d_in[5];
  const float* bo   = (const float*)d_in[6];
  const float* Wg   = (const float*)d_in[7];
  const float* bg   = (const float*)d_in[8];
  float* out = (float*)d_out;

  char* ws = (char*)d_ws;
  size_t off = 0;
  short* Wt1   = (short*)(ws + off); off += (size_t)2048 * 256 * 2;         // 1.0 MiB
  short* WoT   = (short*)(ws + off); off += (size_t)256 * 512 * 2;          // 0.25 MiB
  short* xb    = (short*)(ws + off); off += (size_t)32768 * 256 * 2;        // 16 MiB
  short* Qb    = (short*)(ws + off); off += (size_t)B_ * H_ * N_ * DH_ * 2; // 32 MiB
  short* Kb    = (short*)(ws + off); off += (size_t)B_ * H_ * N_ * DH_ * 2; // 32 MiB
  short* Vt    = (short*)(ws + off); off += (size_t)B_ * H_ * DH_ * N_ * 2; // 32 MiB
  short* G     = (short*)(ws + off); off += (size_t)B_ * N_ * INNER_ * 2;   // 32 MiB
  float* biasS = (float*)(ws + off); off += (size_t)H_ * N_ * N_ * 4;       // 8 MiB
  float* maskF = (float*)(ws + off); off += (size_t)B_ * N_ * 4;            // 128 KiB

  prep_all<<<PREP_KBLK + 160, 256, 0, stream>>>(x, bias, mask, Wq, Wkv, Wg, Wo,
                                                xb, biasS, maskF, Wt1, WoT);
  gemm_qkvg<<<dim3(16, 256), 256, 0, stream>>>(xb, Wt1, bg, Qb, Kb, Vt, G);
  attn_k<<<dim3(8, 4, 64), 256, 0, stream>>>(Qb, Kb, Vt, biasS, maskF, G);
  gemm_og<<<dim3(2, 512), 256, 0, stream>>>(G, WoT, bo, out);
}